// Round 8
// baseline (319.992 us; speedup 1.0000x reference)
//
#include <hip/hip_runtime.h>

#define NN 50000
#define NE 1600000
#define EP (NE + NN)   // edges + self loops
#define IN_DIM 256
#define HIDD 64
#define NCLS 10
#define NBKT 196                       // destination buckets: d >> 8
#define EPB 2048                       // edges per partition block (256 thr x 8)
#define NPB ((EP + EPB - 1) / EPB)     // 806 partition blocks
#define BCAP 12288                     // fixed bucket capacity (exp 8418 +- 92)

typedef unsigned short u16;
typedef short bf16x8 __attribute__((ext_vector_type(8)));
typedef float f32x4 __attribute__((ext_vector_type(4)));

__device__ __forceinline__ float b2f(u16 v) { return __uint_as_float(((unsigned)v) << 16); }
__device__ __forceinline__ u16 f2b(float f) {
    unsigned u = __float_as_uint(f);
    unsigned r = (u + 0x7FFFu + ((u >> 16) & 1u)) >> 16;
    return (u16)r;
}

__device__ __forceinline__ void load_edge(const int* __restrict__ ei, int m, int g,
                                          int& s, int& d) {
    if (g < NE) {
        if (m) { s = ei[2 * (size_t)g]; d = ei[2 * ((size_t)NE + g)]; }
        else   { s = ei[g];             d = ei[NE + g]; }
    } else {
        s = d = g - NE;  // self loop
    }
    s = s < 0 ? 0 : (s >= NN ? NN - 1 : s);
    d = d < 0 ? 0 : (d >= NN ? NN - 1 : d);
}

// ---- weight transpose + augmented score rows (device helper) ----
__device__ __forceinline__ void wcvt_att_job(
    const float* __restrict__ W, const float* __restrict__ as,
    const float* __restrict__ ad, int K, int N, int H, u16* __restrict__ Wt,
    int idx) {
    if (idx >= K * (N + 16)) return;
    int n = idx / K, k = idx - n * K;
    if (n < N) { Wt[idx] = f2b(W[(size_t)k * N + n]); return; }
    int j = n - N;
    if (j >= 2 * H) { Wt[idx] = 0; return; }
    const float* att = (j & 1) ? ad : as;
    int h = j >> 1, C = N / H;
    float sum = 0.f;
    for (int c = 0; c < C; ++c)
        sum += W[(size_t)k * N + h * C + c] * att[h * C + c];
    Wt[idx] = f2b(sum);
}

// ---- kernel 0: weight conversion + gcursor zeroing (replaces memset) ----
__global__ __launch_bounds__(256) void wcvt_k(
    const float* __restrict__ W1, const float* __restrict__ as1,
    const float* __restrict__ ad1, u16* __restrict__ w1t,
    const float* __restrict__ W2, const float* __restrict__ as2,
    const float* __restrict__ ad2, u16* __restrict__ w2t,
    int* __restrict__ gcursor) {
    int b = blockIdx.x, t = threadIdx.x;
    if (b < 144) wcvt_att_job(W1, as1, ad1, 256, 128, 2, w1t, b * 256 + t);
    else if (b < 184) wcvt_att_job(W2, as2, ad2, 128, 64, 1, w2t, (b - 144) * 256 + t);
    else {
        if (t < NBKT) gcursor[t] = 0;
    }
}

// ---- partition body: single-read (reg stash) + vectorized edge loads ----
__device__ void partition_body(int b, const int* __restrict__ ei,
                               int* __restrict__ gcursor,
                               unsigned* __restrict__ bbuf) {
    __shared__ int hist[NBKT], base[NBKT], lbase[NBKT], lcur[NBKT];
    __shared__ int psc[256];
    __shared__ unsigned sst[EPB];
    __shared__ int smode;
    int t = threadIdx.x;
    if (t < 64) {
        int nz = 0;
#pragma unroll
        for (int k = 0; k < 4; ++k)
            if (ei[2 * (t * 4 + k) + 1] != 0) nz = 1;
        unsigned long long bal = __ballot(nz);
        if (t == 0) smode = (bal == 0ULL) ? 1 : 0;  // 1 = int64 layout
    }
    for (int i = t; i < NBKT; i += 256) hist[i] = 0;
    __syncthreads();
    int m = smode;
    int g0 = b * EPB, gend = min(g0 + EPB, EP);
    unsigned ed[8];
#pragma unroll
    for (int i = 0; i < 4; ++i) {
        int g = g0 + i * 512 + 2 * t;
        int s0 = 0, d0 = 0, s1 = 0, d1 = 0;
        bool v0 = g < gend, v1 = g + 1 < gend;
        if (v1 && g >= NE) {            // pure self-loop pair: no load
            s0 = d0 = g - NE; s1 = d1 = g + 1 - NE;
        } else if (v1 && g + 1 < NE) {  // pure edge pair: vector load
            if (m) {
                int4 sv = *(const int4*)(ei + 2 * (size_t)g);
                int4 dv = *(const int4*)(ei + 2 * ((size_t)NE + g));
                s0 = sv.x; s1 = sv.z; d0 = dv.x; d1 = dv.z;
            } else {
                int2 sv = *(const int2*)(ei + g);
                int2 dv = *(const int2*)(ei + NE + g);
                s0 = sv.x; s1 = sv.y; d0 = dv.x; d1 = dv.y;
            }
            s0 = s0 < 0 ? 0 : (s0 >= NN ? NN - 1 : s0);
            d0 = d0 < 0 ? 0 : (d0 >= NN ? NN - 1 : d0);
            s1 = s1 < 0 ? 0 : (s1 >= NN ? NN - 1 : s1);
            d1 = d1 < 0 ? 0 : (d1 >= NN ? NN - 1 : d1);
        } else {                        // boundary / tail: scalar
            if (v0) load_edge(ei, m, g, s0, d0);
            if (v1) load_edge(ei, m, g + 1, s1, d1);
        }
        if (v0) { ed[2 * i] = ((unsigned)s0 << 16) | (unsigned)d0; atomicAdd(&hist[d0 >> 8], 1); }
        else ed[2 * i] = 0xFFFFFFFFu;
        if (v1) { ed[2 * i + 1] = ((unsigned)s1 << 16) | (unsigned)d1; atomicAdd(&hist[d1 >> 8], 1); }
        else ed[2 * i + 1] = 0xFFFFFFFFu;
    }
    __syncthreads();
    int hv = (t < NBKT) ? hist[t] : 0;
    psc[t] = hv;
    __syncthreads();
    for (int off = 1; off < 256; off <<= 1) {
        int x = (t >= off) ? psc[t - off] : 0;
        __syncthreads();
        psc[t] += x;
        __syncthreads();
    }
    if (t < NBKT) {
        lbase[t] = psc[t] - hv;
        lcur[t] = 0;
        base[t] = hv ? atomicAdd(&gcursor[t], hv) : 0;
    }
    __syncthreads();
#pragma unroll
    for (int i = 0; i < 8; ++i) {
        unsigned p = ed[i];
        if (p != 0xFFFFFFFFu) {
            int bb = (p & 0xFFFF) >> 8;
            int r = lbase[bb] + atomicAdd(&lcur[bb], 1);
            sst[r] = p;
        }
    }
    __syncthreads();
    int cnt = gend - g0;
    for (int l = t; l < cnt; l += 256) {
        unsigned p = sst[l];
        int bb = (p & 0xFFFF) >> 8;
        int gp = base[bb] + (l - lbase[bb]);
        if (gp < BCAP)
            bbuf[(size_t)bb * BCAP + gp] = ((p >> 16) << 8) | (p & 255u);
    }
}

// ---- MFMA GEMM body (shared by fused kernel + gemm2) ----
template <int K, int NF, int H, bool F32A, bool SLICED_A, bool SLICED_C>
__device__ __forceinline__ void gemm_body(
    int bb, const float* __restrict__ Af, const u16* __restrict__ Ab,
    const u16* __restrict__ Wt, u16* __restrict__ C,
    float* __restrict__ a_s, float* __restrict__ a_d) {
    constexpr int NTF = NF / 16, NT = NTF + 1, KS = K / 32;
    const int wave = threadIdx.x >> 6, lane = threadIdx.x & 63;
    const int quad = lane >> 4, l15 = lane & 15;
    const int m0 = bb * 64 + wave * 16;
    int rowA = m0 + l15;
    if (rowA >= NN) rowA = NN - 1;
    const float* afp = F32A ? (Af + (size_t)rowA * K + quad * 8) : nullptr;
    const u16* abp = nullptr;
    if constexpr (!F32A) {
        abp = SLICED_A ? (Ab + (size_t)rowA * 32 + quad * 8)
                       : (Ab + (size_t)rowA * K + quad * 8);
    }
    const u16* bptr = Wt + (size_t)l15 * K + quad * 8;
    f32x4 acc[NT] = {};
#pragma unroll
    for (int ks = 0; ks < KS; ++ks) {
        bf16x8 af;
        if constexpr (F32A) {
            float4 v0 = *(const float4*)(afp + ks * 32);
            float4 v1 = *(const float4*)(afp + ks * 32 + 4);
            af[0] = (short)f2b(v0.x); af[1] = (short)f2b(v0.y);
            af[2] = (short)f2b(v0.z); af[3] = (short)f2b(v0.w);
            af[4] = (short)f2b(v1.x); af[5] = (short)f2b(v1.y);
            af[6] = (short)f2b(v1.z); af[7] = (short)f2b(v1.w);
        } else {
            af = SLICED_A ? *(const bf16x8*)(abp + (size_t)ks * (NN * 32))
                          : *(const bf16x8*)(abp + ks * 32);
        }
        bf16x8 bf[NT];
#pragma unroll
        for (int nt = 0; nt < NT; ++nt)
            bf[nt] = *(const bf16x8*)(bptr + (size_t)nt * 16 * K + ks * 32);
#pragma unroll
        for (int nt = 0; nt < NT; ++nt)
            acc[nt] = __builtin_amdgcn_mfma_f32_16x16x32_bf16(af, bf[nt], acc[nt], 0, 0, 0);
    }
#pragma unroll
    for (int nt = 0; nt < NTF; ++nt) {
#pragma unroll
        for (int reg = 0; reg < 4; ++reg) {
            int row = m0 + quad * 4 + reg;
            int c = nt * 16 + l15;
            if (row < NN) {
                if constexpr (SLICED_C)
                    C[(size_t)(c >> 5) * (NN * 32) + (size_t)row * 32 + (c & 31)] =
                        f2b(acc[nt][reg]);
                else
                    C[(size_t)row * NF + c] = f2b(acc[nt][reg]);
            }
        }
    }
    if (l15 < 2 * H) {
        int h = l15 >> 1;
        float* dst = (l15 & 1) ? a_d : a_s;
#pragma unroll
        for (int reg = 0; reg < 4; ++reg) {
            int row = m0 + quad * 4 + reg;
            if (row < NN) dst[row * H + h] = acc[NTF][reg];
        }
    }
}

// ---- fused: partition (blocks 0..NPB-1) || layer-1 GEMM (blocks NPB..) ----
__global__ __launch_bounds__(256) void part_gemm_k(
    const int* __restrict__ ei, int* __restrict__ gcursor,
    unsigned* __restrict__ bbuf, const float* __restrict__ x,
    const u16* __restrict__ w1t, u16* __restrict__ hb,
    float* __restrict__ a_s, float* __restrict__ a_d) {
    if (blockIdx.x < NPB)
        partition_body(blockIdx.x, ei, gcursor, bbuf);
    else
        gemm_body<256, 128, 2, true, false, false>(blockIdx.x - NPB, x, nullptr,
                                                   w1t, hb, a_s, a_d);
}

// ---- standalone layer-2 GEMM: h2 row-major [NN][64] ----
__global__ __launch_bounds__(256) void gemm2_k(
    const u16* __restrict__ Ab, const u16* __restrict__ Wt, u16* __restrict__ C,
    float* __restrict__ a_s, float* __restrict__ a_d) {
    gemm_body<128, 64, 1, false, true, false>(blockIdx.x, nullptr, Ab, Wt, C, a_s, a_d);
}

// ---- per-bucket fine CSR; LDS sort -> COALESCED csr_src writes ----
__global__ __launch_bounds__(1024) void bucket_csr_k(const unsigned* __restrict__ bbuf,
                                                     const int* __restrict__ gcursor,
                                                     int* __restrict__ row_ptr,
                                                     u16* __restrict__ csr_src) {
    __shared__ int bsc[256];
    __shared__ int hist[256], scn[256], cur[256];
    __shared__ int se0, scnt, stot;
    __shared__ u16 srt[BCAP];
    int b = blockIdx.x, t = threadIdx.x;
    int v = 0;
    if (t < 256) {
        v = (t < NBKT) ? min(gcursor[t], BCAP) : 0;
        bsc[t] = v;
        hist[t] = 0;
    }
    __syncthreads();
    for (int off = 1; off < 256; off <<= 1) {
        int x = (t < 256 && t >= off) ? bsc[t - off] : 0;
        __syncthreads();
        if (t < 256) bsc[t] += x;
        __syncthreads();
    }
    if (t == b) { se0 = bsc[t] - v; scnt = v; }
    if (t == NBKT - 1) stot = bsc[t];
    __syncthreads();
    int e0 = se0, cnt = scnt;
    const unsigned* bb = bbuf + (size_t)b * BCAP;
    for (int e = t; e < cnt; e += 1024)
        atomicAdd(&hist[bb[e] & 255], 1);
    __syncthreads();
    int hv = 0;
    if (t < 256) { hv = hist[t]; scn[t] = hv; }
    __syncthreads();
    for (int off = 1; off < 256; off <<= 1) {
        int x = (t < 256 && t >= off) ? scn[t - off] : 0;
        __syncthreads();
        if (t < 256) scn[t] += x;
        __syncthreads();
    }
    if (t < 256) {
        int ex = scn[t] - hv;  // exclusive within bucket (LOCAL offset)
        int n = b * 256 + t;
        if (n < NN) row_ptr[n] = e0 + ex;
        cur[t] = ex;
    }
    __syncthreads();
    for (int e = t; e < cnt; e += 1024) {
        unsigned p = bb[e];
        int pos = atomicAdd(&cur[p & 255], 1);
        srt[pos] = (u16)(p >> 8);
    }
    __syncthreads();
    for (int e = t; e < cnt; e += 1024)
        csr_src[e0 + e] = srt[e];
    if (b == 0 && t == 0) row_ptr[NN] = stot;
}

// ---- layer-1 fused gather (roofline-verified 64us): one WAVE per node ----
template <int CH, int H, bool HEAD>
__global__ __launch_bounds__(256) void gat_gather_k(
    const int* __restrict__ row_ptr, const u16* __restrict__ csr_src,
    const float* __restrict__ a_s, const float* __restrict__ a_d,
    const u16* __restrict__ h, const float* __restrict__ bias,
    u16* __restrict__ outg, const float* __restrict__ Wl,
    const float* __restrict__ bl, float* __restrict__ outh) {
    constexpr int VEC = CH / 64;
    constexpr int JB = 16;
    int n = (blockIdx.x * blockDim.x + threadIdx.x) >> 6;  // global wave id = node
    int lane = threadIdx.x & 63;
    if (n >= NN) return;  // wave-uniform exit
    int r0 = row_ptr[n], r1 = row_ptr[n + 1];
    const bool hi = (VEC == 2) ? (lane >= 32) : false;
    const int shl16 = hi ? 0 : 16;  // select my head's bf16 ex into bits 31..16

    float adn0, adn1 = 0.f;
    if (H == 2) {
        float2 adv = *(const float2*)(a_d + n * 2);
        adn0 = adv.x; adn1 = adv.y;
    } else {
        adn0 = a_d[n];
    }

    float dh0 = 0.f, dh1 = 0.f;
    float acc[VEC];
#pragma unroll
    for (int v = 0; v < VEC; ++v) acc[v] = 0.f;

    for (int base = r0; base < r1; base += 64) {
        int cnt = min(64, r1 - base);
        int idx = base + lane;
        bool act = idx < r1;
        int sl = act ? (int)csr_src[idx] : 0;
        unsigned pex;   // H==2: bf16(ex0)|bf16(ex1)<<16 ; H==1: s|bf16(ex)<<16
        if (H == 2) {
            float2 av = *(const float2*)(a_s + sl * 2);
            float e0 = av.x + adn0;
            e0 = e0 > 0.f ? e0 : 0.2f * e0;
            e0 = fminf(e0, 60.f);
            float ex0 = act ? __expf(e0) : 0.f;
            dh0 += ex0;
            float e1 = av.y + adn1;
            e1 = e1 > 0.f ? e1 : 0.2f * e1;
            e1 = fminf(e1, 60.f);
            float ex1 = act ? __expf(e1) : 0.f;
            dh1 += ex1;
            pex = (unsigned)f2b(ex0) | ((unsigned)f2b(ex1) << 16);
        } else {
            float e0 = a_s[sl] + adn0;
            e0 = e0 > 0.f ? e0 : 0.2f * e0;
            e0 = fminf(e0, 60.f);
            float ex0 = act ? __expf(e0) : 0.f;
            dh0 += ex0;
            pex = (unsigned)sl | ((unsigned)f2b(ex0) << 16);
        }
        for (int j0 = 0; j0 < cnt; j0 += JB) {
            if (VEC == 2) {
                int ssu[JB];
                unsigned peu[JB];
#pragma unroll
                for (int i = 0; i < JB; ++i) {
                    ssu[i] = __builtin_amdgcn_readlane(sl, j0 + i);
                    peu[i] = (unsigned)__builtin_amdgcn_readlane((int)pex, j0 + i);
                }
                unsigned hv[JB];
#pragma unroll
                for (int i = 0; i < JB; ++i)
                    hv[i] = ((const unsigned*)(h + (size_t)ssu[i] * CH))[lane];
#pragma unroll
                for (int i = 0; i < JB; ++i) {
                    float exv = __uint_as_float((peu[i] << shl16) & 0xFFFF0000u);
                    acc[0] += exv * __uint_as_float(hv[i] << 16);
                    acc[1] += exv * __uint_as_float(hv[i] & 0xFFFF0000u);
                }
            } else {
                unsigned peu[JB];
#pragma unroll
                for (int i = 0; i < JB; ++i)
                    peu[i] = (unsigned)__builtin_amdgcn_readlane((int)pex, j0 + i);
                u16 hv[JB];
#pragma unroll
                for (int i = 0; i < JB; ++i)
                    hv[i] = (h + (size_t)(peu[i] & 0xFFFFu) * CH)[lane];
#pragma unroll
                for (int i = 0; i < JB; ++i)
                    acc[0] += __uint_as_float(peu[i] & 0xFFFF0000u) * b2f(hv[i]);
            }
        }
    }

#pragma unroll
    for (int off = 32; off; off >>= 1) dh0 += __shfl_xor(dh0, off);
    float dn = dh0;
    if (H == 2) {
#pragma unroll
        for (int off = 32; off; off >>= 1) dh1 += __shfl_xor(dh1, off);
        dn = hi ? dh1 : dh0;
    }

    if (VEC == 2) {
        int c = lane * 2;
        float2 bv = *(const float2*)(bias + c);
        float v0 = acc[0] / dn + bv.x;
        float v1 = acc[1] / dn + bv.y;
        v0 = v0 > 0.f ? v0 : expm1f(v0);
        v1 = v1 > 0.f ? v1 : expm1f(v1);
        ushort2 ov;
        ov.x = f2b(v0); ov.y = f2b(v1);
        // slice-major store: slice = c>>5, offset within = c&31
        *(ushort2*)(outg + (size_t)(c >> 5) * (NN * 32) + (size_t)n * 32 + (c & 31)) = ov;
    } else {
        float v0 = acc[0] / dn + bias[lane];
        v0 = v0 > 0.f ? v0 : expm1f(v0);
        outg[(size_t)n * CH + lane] = f2b(v0);
    }
}

// ---- per-edge alpha precompute for layer 2: A2[e] = src | bf16(ex)<<16 ----
__global__ __launch_bounds__(256) void edge_alpha_k(
    const int* __restrict__ row_ptr, const u16* __restrict__ csr_src,
    const float* __restrict__ a_s, const float* __restrict__ a_d,
    unsigned* __restrict__ A2, float* __restrict__ dninv) {
    int wave = threadIdx.x >> 6;
    int pair = blockIdx.x * 4 + wave;
    if (pair >= NN / 2) return;
    int lane = threadIdx.x & 63, half = lane >> 5, hl = lane & 31;
    int node = pair * 2 + half;
    int r0 = row_ptr[node], r1 = row_ptr[node + 1];
    int cnt = r1 - r0;
    int co = max(cnt, __shfl_xor(cnt, 32));
    int nbat = (co + 31) >> 5;
    float adn = a_d[node];
    float dh = 0.f;
    for (int b = 0; b < nbat; ++b) {
        int idx = r0 + b * 32 + hl;
        bool act = idx < r1;
        int sl = act ? (int)csr_src[idx] : 0;
        float e = a_s[sl] + adn;
        e = e > 0.f ? e : 0.2f * e;
        e = fminf(e, 60.f);
        float ex = act ? __expf(e) : 0.f;
        dh += ex;
        if (act)
            __builtin_nontemporal_store(
                (unsigned)sl | ((unsigned)f2b(ex) << 16), A2 + idx);
    }
#pragma unroll
    for (int off = 1; off < 32; off <<= 1) dh += __shfl_xor(dh, off);
    if (hl == 0) dninv[node] = 1.0f / dh;
}

// ---- layer-2 one-pass gather + ELU + fused head: one WAVE per node ----
// Per edge: 8 lanes x 16B cover the 128B h2 row (8 edges per bpermute
// round); alpha from A2 (no per-edge score work, no a_s requests).
// Floor: 1.65M x 128B = 211MB row reads (~32us at gather1's rate).
__global__ __launch_bounds__(256) void gat2_head_k(
    const int* __restrict__ row_ptr, const unsigned* __restrict__ A2,
    const float* __restrict__ dninv, const u16* __restrict__ h,
    const float* __restrict__ bias, const float* __restrict__ Wl,
    const float* __restrict__ bl, float* __restrict__ out) {
    int n = (blockIdx.x * blockDim.x + threadIdx.x) >> 6;  // wave id = node
    int lane = threadIdx.x & 63;
    if (n >= NN) return;  // wave-uniform
    int r0 = row_ptr[n], r1 = row_ptr[n + 1];
    int q = lane & 7, g = lane >> 3;
    float rdn = dninv[n];
    float acc[8];
#pragma unroll
    for (int v = 0; v < 8; ++v) acc[v] = 0.f;

    for (int base = r0; base < r1; base += 64) {
        int cnt = min(64, r1 - base);
        int idx = base + lane;
        unsigned pex = (idx < r1) ? __builtin_nontemporal_load(A2 + idx) : 0u;
        for (int j0 = 0; j0 < cnt; j0 += 8) {
            int pr = __builtin_amdgcn_ds_bpermute((j0 + g) << 2, (int)pex);
            // padded slots (j0+g >= cnt) have pex=0 -> exf=0, row 0: safe
            float exf = __uint_as_float((unsigned)pr & 0xFFFF0000u);
            const unsigned* p = (const unsigned*)(
                h + (size_t)((unsigned)pr & 0xFFFFu) * 64 + q * 8);
            unsigned w0 = p[0], w1 = p[1], w2 = p[2], w3 = p[3];
            acc[0] += exf * __uint_as_float(w0 << 16);
            acc[1] += exf * __uint_as_float(w0 & 0xFFFF0000u);
            acc[2] += exf * __uint_as_float(w1 << 16);
            acc[3] += exf * __uint_as_float(w1 & 0xFFFF0000u);
            acc[4] += exf * __uint_as_float(w2 << 16);
            acc[5] += exf * __uint_as_float(w2 & 0xFFFF0000u);
            acc[6] += exf * __uint_as_float(w3 << 16);
            acc[7] += exf * __uint_as_float(w3 & 0xFFFF0000u);
        }
    }
    // reduce partials across the 8 row-groups (lanes with same q)
#pragma unroll
    for (int v = 0; v < 8; ++v) {
        acc[v] += __shfl_xor(acc[v], 8);
        acc[v] += __shfl_xor(acc[v], 16);
        acc[v] += __shfl_xor(acc[v], 32);
    }
    // redistribute so lane l holds channel l (verified round-1 block):
    // select acc[l>>3] via cndmask tree, bpermute from ((l&7)<<3)|(l>>3)
    float t01 = (lane & 8) ? acc[1] : acc[0];
    float t23 = (lane & 8) ? acc[3] : acc[2];
    float t45 = (lane & 8) ? acc[5] : acc[4];
    float t67 = (lane & 8) ? acc[7] : acc[6];
    float ta = (lane & 16) ? t23 : t01;
    float tb = (lane & 16) ? t67 : t45;
    float ts = (lane & 32) ? tb : ta;
    int srcl = ((lane & 7) << 3) | (lane >> 3);
    float vsw = __uint_as_float(
        __builtin_amdgcn_ds_bpermute(srcl << 2, __float_as_int(ts)));
    float v0 = vsw * rdn + bias[lane];
    v0 = v0 > 0.f ? v0 : expm1f(v0);
#pragma unroll
    for (int cls = 0; cls < NCLS; ++cls) {
        float p = v0 * Wl[lane * NCLS + cls];
#pragma unroll
        for (int off = 32; off; off >>= 1) p += __shfl_xor(p, off);
        if (lane == cls) out[(size_t)n * NCLS + cls] = p + bl[cls];
    }
}

extern "C" void kernel_launch(void* const* d_in, const int* in_sizes, int n_in,
                              void* d_out, int out_size, void* d_ws, size_t ws_size,
                              hipStream_t stream) {
    const float* x   = (const float*)d_in[0];
    const int*   ei  = (const int*)d_in[1];
    const float* W1  = (const float*)d_in[2];
    const float* as1 = (const float*)d_in[3];
    const float* ad1 = (const float*)d_in[4];
    const float* b1  = (const float*)d_in[5];
    const float* W2  = (const float*)d_in[6];
    const float* as2 = (const float*)d_in[7];
    const float* ad2 = (const float*)d_in[8];
    const float* b2  = (const float*)d_in[9];
    const float* Wl  = (const float*)d_in[10];
    const float* bl  = (const float*)d_in[11];
    float* out = (float*)d_out;

    // ---- workspace layout (~30 MB) ----
    float* ws = (float*)d_ws;
    size_t o = 0;
    u16* hb  = (u16*)(ws + o); o += (size_t)NN * 64;  // h1 [NN][128] / h2 [NN][64] row-major
    u16* g1  = (u16*)(ws + o); o += (size_t)NN * 64;  // g1 [4][NN][32]; bbuf overlay; A2 overlay
    unsigned* bbuf = (unsigned*)g1;                   // 9.63 MB <= 12.8 MB (until bucket_csr)
    unsigned* A2 = (unsigned*)g1;                     // 6.6 MB (after gemm2 consumed g1)
    float* dn2inv = (float*)((char*)g1 + (size_t)EP * 4);  // +200 KB, still in g1
    u16* w1t = (u16*)(ws + o); o += 144 * 256 / 2;    // bf16 W1^T+att [144][256]
    u16* w2t = (u16*)(ws + o); o += 80 * 128 / 2;     // bf16 W2^T+att [80][128]
    float* a_s = ws + o;       o += (size_t)NN * 2;
    float* a_d = ws + o;       o += (size_t)NN * 2;
    int* ints = (int*)(ws + o);
    size_t io = 0;
    int* gcursor  = ints + io; io += NBKT;
    int* row_ptr  = ints + io; io += NN + 1;
    u16* csr_src  = (u16*)(ints + io); io += (EP + 1) / 2;

    const int gemmBlocks = (NN + 63) / 64;  // 782
    const int gatherBlocks = (NN + 3) / 4;  // 4 waves (nodes) per 256-thread block

    // K0: weight conversion + gcursor zero
    wcvt_k<<<185, 256, 0, stream>>>(W1, as1, ad1, w1t, W2, as2, ad2, w2t, gcursor);
    // K1: partition (blocks 0..805) || layer-1 GEMM (blocks 806..1587)
    part_gemm_k<<<NPB + gemmBlocks, 256, 0, stream>>>(
        ei, gcursor, bbuf, x, w1t, hb, a_s, a_d);
    // K2: per-bucket fine CSR
    bucket_csr_k<<<NBKT, 1024, 0, stream>>>(bbuf, gcursor, row_ptr, csr_src);
    // K3: layer-1 gather + ELU (writes g1 slice-major)
    gat_gather_k<128, 2, false><<<gatherBlocks, 256, 0, stream>>>(
        row_ptr, csr_src, a_s, a_d, hb, b1, g1, nullptr, nullptr, nullptr);
    // K4: layer-2 GEMM (sliced A, row-major h2 out)
    gemm2_k<<<gemmBlocks, 256, 0, stream>>>(g1, w2t, hb, a_s, a_d);
    // K5: layer-2 per-edge alpha (A2 overlays g1, now dead)
    edge_alpha_k<<<(NN / 2 + 3) / 4, 256, 0, stream>>>(
        row_ptr, csr_src, a_s, a_d, A2, dn2inv);
    // K6: layer-2 one-pass gather + ELU + head (replaces slice2 + head GEMM)
    gat2_head_k<<<gatherBlocks, 256, 0, stream>>>(
        row_ptr, A2, dn2inv, hb, b2, Wl, bl, out);
}

// Round 11
// 319.016 us; speedup vs baseline: 1.0031x; 1.0031x over previous
//
#include <hip/hip_runtime.h>

#define NN 50000
#define NE 1600000
#define EP (NE + NN)   // edges + self loops
#define IN_DIM 256
#define HIDD 64
#define NCLS 10
#define NBKT 196                       // destination buckets: d >> 8
#define EPB 2048                       // edges per partition block (256 thr x 8)
#define NPB ((EP + EPB - 1) / EPB)     // 806 partition blocks
#define BCAP 12288                     // fixed bucket capacity (exp 8418 +- 92)
#define QS 4                           // bucket_csr quarter-split
#define QCAP 3072                      // per-quarter capacity (exp ~2105 +- 46)

typedef unsigned short u16;
typedef short bf16x8 __attribute__((ext_vector_type(8)));
typedef float f32x4 __attribute__((ext_vector_type(4)));

__device__ __forceinline__ float b2f(u16 v) { return __uint_as_float(((unsigned)v) << 16); }
__device__ __forceinline__ u16 f2b(float f) {
    unsigned u = __float_as_uint(f);
    unsigned r = (u + 0x7FFFu + ((u >> 16) & 1u)) >> 16;
    return (u16)r;
}

__device__ __forceinline__ void load_edge(const int* __restrict__ ei, int m, int g,
                                          int& s, int& d) {
    if (g < NE) {
        if (m) { s = ei[2 * (size_t)g]; d = ei[2 * ((size_t)NE + g)]; }
        else   { s = ei[g];             d = ei[NE + g]; }
    } else {
        s = d = g - NE;  // self loop
    }
    s = s < 0 ? 0 : (s >= NN ? NN - 1 : s);
    d = d < 0 ? 0 : (d >= NN ? NN - 1 : d);
}

// ---- weight transpose + augmented score rows (device helper) ----
__device__ __forceinline__ void wcvt_att_job(
    const float* __restrict__ W, const float* __restrict__ as,
    const float* __restrict__ ad, int K, int N, int H, u16* __restrict__ Wt,
    int idx) {
    if (idx >= K * (N + 16)) return;
    int n = idx / K, k = idx - n * K;
    if (n < N) { Wt[idx] = f2b(W[(size_t)k * N + n]); return; }
    int j = n - N;
    if (j >= 2 * H) { Wt[idx] = 0; return; }
    const float* att = (j & 1) ? ad : as;
    int h = j >> 1, C = N / H;
    float sum = 0.f;
    for (int c = 0; c < C; ++c)
        sum += W[(size_t)k * N + h * C + c] * att[h * C + c];
    Wt[idx] = f2b(sum);
}

// ---- kernel 0: weight conversion + Wl transpose + gcursor zeroing ----
__global__ __launch_bounds__(256) void wcvt_k(
    const float* __restrict__ W1, const float* __restrict__ as1,
    const float* __restrict__ ad1, u16* __restrict__ w1t,
    const float* __restrict__ W2, const float* __restrict__ as2,
    const float* __restrict__ ad2, u16* __restrict__ w2t,
    const float* __restrict__ Wl, u16* __restrict__ wlt,
    int* __restrict__ gcursor) {
    int b = blockIdx.x, t = threadIdx.x;
    if (b < 144) wcvt_att_job(W1, as1, ad1, 256, 128, 2, w1t, b * 256 + t);
    else if (b < 184) wcvt_att_job(W2, as2, ad2, 128, 64, 1, w2t, (b - 144) * 256 + t);
    else if (b < 188) {
        int idx = (b - 184) * 256 + t;
        int n = idx >> 6, k = idx & 63;  // wlt[16][64] = Wl^T padded
        wlt[n * 64 + k] = (n < NCLS) ? f2b(Wl[k * NCLS + n]) : (u16)0;
    } else {
        if (t < NBKT) gcursor[t] = 0;
    }
}

// ---- partition body: single-read (reg stash) + vectorized edge loads ----
__device__ void partition_body(int b, const int* __restrict__ ei,
                               int* __restrict__ gcursor,
                               unsigned* __restrict__ bbuf) {
    __shared__ int hist[NBKT], base[NBKT], lbase[NBKT], lcur[NBKT];
    __shared__ int psc[256];
    __shared__ unsigned sst[EPB];
    __shared__ int smode;
    int t = threadIdx.x;
    if (t < 64) {
        int nz = 0;
#pragma unroll
        for (int k = 0; k < 4; ++k)
            if (ei[2 * (t * 4 + k) + 1] != 0) nz = 1;
        unsigned long long bal = __ballot(nz);
        if (t == 0) smode = (bal == 0ULL) ? 1 : 0;  // 1 = int64 layout
    }
    for (int i = t; i < NBKT; i += 256) hist[i] = 0;
    __syncthreads();
    int m = smode;
    int g0 = b * EPB, gend = min(g0 + EPB, EP);
    unsigned ed[8];
#pragma unroll
    for (int i = 0; i < 4; ++i) {
        int g = g0 + i * 512 + 2 * t;
        int s0 = 0, d0 = 0, s1 = 0, d1 = 0;
        bool v0 = g < gend, v1 = g + 1 < gend;
        if (v1 && g >= NE) {            // pure self-loop pair: no load
            s0 = d0 = g - NE; s1 = d1 = g + 1 - NE;
        } else if (v1 && g + 1 < NE) {  // pure edge pair: vector load
            if (m) {
                int4 sv = *(const int4*)(ei + 2 * (size_t)g);
                int4 dv = *(const int4*)(ei + 2 * ((size_t)NE + g));
                s0 = sv.x; s1 = sv.z; d0 = dv.x; d1 = dv.z;
            } else {
                int2 sv = *(const int2*)(ei + g);
                int2 dv = *(const int2*)(ei + NE + g);
                s0 = sv.x; s1 = sv.y; d0 = dv.x; d1 = dv.y;
            }
            s0 = s0 < 0 ? 0 : (s0 >= NN ? NN - 1 : s0);
            d0 = d0 < 0 ? 0 : (d0 >= NN ? NN - 1 : d0);
            s1 = s1 < 0 ? 0 : (s1 >= NN ? NN - 1 : s1);
            d1 = d1 < 0 ? 0 : (d1 >= NN ? NN - 1 : d1);
        } else {                        // boundary / tail: scalar
            if (v0) load_edge(ei, m, g, s0, d0);
            if (v1) load_edge(ei, m, g + 1, s1, d1);
        }
        if (v0) { ed[2 * i] = ((unsigned)s0 << 16) | (unsigned)d0; atomicAdd(&hist[d0 >> 8], 1); }
        else ed[2 * i] = 0xFFFFFFFFu;
        if (v1) { ed[2 * i + 1] = ((unsigned)s1 << 16) | (unsigned)d1; atomicAdd(&hist[d1 >> 8], 1); }
        else ed[2 * i + 1] = 0xFFFFFFFFu;
    }
    __syncthreads();
    int hv = (t < NBKT) ? hist[t] : 0;
    psc[t] = hv;
    __syncthreads();
    for (int off = 1; off < 256; off <<= 1) {
        int x = (t >= off) ? psc[t - off] : 0;
        __syncthreads();
        psc[t] += x;
        __syncthreads();
    }
    if (t < NBKT) {
        lbase[t] = psc[t] - hv;
        lcur[t] = 0;
        base[t] = hv ? atomicAdd(&gcursor[t], hv) : 0;
    }
    __syncthreads();
#pragma unroll
    for (int i = 0; i < 8; ++i) {
        unsigned p = ed[i];
        if (p != 0xFFFFFFFFu) {
            int bb = (p & 0xFFFF) >> 8;
            int r = lbase[bb] + atomicAdd(&lcur[bb], 1);
            sst[r] = p;
        }
    }
    __syncthreads();
    int cnt = gend - g0;
    for (int l = t; l < cnt; l += 256) {
        unsigned p = sst[l];
        int bb = (p & 0xFFFF) >> 8;
        int gp = base[bb] + (l - lbase[bb]);
        if (gp < BCAP)
            bbuf[(size_t)bb * BCAP + gp] = ((p >> 16) << 8) | (p & 255u);
    }
}

// ---- MFMA GEMM body (shared by fused kernel + gemm2) ----
template <int K, int NF, int H, bool F32A, bool SLICED_A, bool SLICED_C>
__device__ __forceinline__ void gemm_body(
    int bb, const float* __restrict__ Af, const u16* __restrict__ Ab,
    const u16* __restrict__ Wt, u16* __restrict__ C,
    float* __restrict__ a_s, float* __restrict__ a_d) {
    constexpr int NTF = NF / 16, NT = NTF + 1, KS = K / 32;
    const int wave = threadIdx.x >> 6, lane = threadIdx.x & 63;
    const int quad = lane >> 4, l15 = lane & 15;
    const int m0 = bb * 64 + wave * 16;
    int rowA = m0 + l15;
    if (rowA >= NN) rowA = NN - 1;
    const float* afp = F32A ? (Af + (size_t)rowA * K + quad * 8) : nullptr;
    const u16* abp = nullptr;
    if constexpr (!F32A) {
        abp = SLICED_A ? (Ab + (size_t)rowA * 32 + quad * 8)
                       : (Ab + (size_t)rowA * K + quad * 8);
    }
    const u16* bptr = Wt + (size_t)l15 * K + quad * 8;
    f32x4 acc[NT] = {};
#pragma unroll
    for (int ks = 0; ks < KS; ++ks) {
        bf16x8 af;
        if constexpr (F32A) {
            float4 v0 = *(const float4*)(afp + ks * 32);
            float4 v1 = *(const float4*)(afp + ks * 32 + 4);
            af[0] = (short)f2b(v0.x); af[1] = (short)f2b(v0.y);
            af[2] = (short)f2b(v0.z); af[3] = (short)f2b(v0.w);
            af[4] = (short)f2b(v1.x); af[5] = (short)f2b(v1.y);
            af[6] = (short)f2b(v1.z); af[7] = (short)f2b(v1.w);
        } else {
            af = SLICED_A ? *(const bf16x8*)(abp + (size_t)ks * (NN * 32))
                          : *(const bf16x8*)(abp + ks * 32);
        }
        bf16x8 bf[NT];
#pragma unroll
        for (int nt = 0; nt < NT; ++nt)
            bf[nt] = *(const bf16x8*)(bptr + (size_t)nt * 16 * K + ks * 32);
#pragma unroll
        for (int nt = 0; nt < NT; ++nt)
            acc[nt] = __builtin_amdgcn_mfma_f32_16x16x32_bf16(af, bf[nt], acc[nt], 0, 0, 0);
    }
#pragma unroll
    for (int nt = 0; nt < NTF; ++nt) {
#pragma unroll
        for (int reg = 0; reg < 4; ++reg) {
            int row = m0 + quad * 4 + reg;
            int c = nt * 16 + l15;
            if (row < NN) {
                if constexpr (SLICED_C)
                    C[(size_t)(c >> 5) * (NN * 32) + (size_t)row * 32 + (c & 31)] =
                        f2b(acc[nt][reg]);
                else
                    C[(size_t)row * NF + c] = f2b(acc[nt][reg]);
            }
        }
    }
    if (l15 < 2 * H) {
        int h = l15 >> 1;
        float* dst = (l15 & 1) ? a_d : a_s;
#pragma unroll
        for (int reg = 0; reg < 4; ++reg) {
            int row = m0 + quad * 4 + reg;
            if (row < NN) dst[row * H + h] = acc[NTF][reg];
        }
    }
}

// ---- fused: partition (blocks 0..NPB-1) || layer-1 GEMM (blocks NPB..) ----
__global__ __launch_bounds__(256) void part_gemm_k(
    const int* __restrict__ ei, int* __restrict__ gcursor,
    unsigned* __restrict__ bbuf, const float* __restrict__ x,
    const u16* __restrict__ w1t, u16* __restrict__ hb,
    float* __restrict__ a_s, float* __restrict__ a_d) {
    if (blockIdx.x < NPB)
        partition_body(blockIdx.x, ei, gcursor, bbuf);
    else
        gemm_body<256, 128, 2, true, false, false>(blockIdx.x - NPB, x, nullptr,
                                                   w1t, hb, a_s, a_d);
}

// ---- standalone layer-2 GEMM: h2 slice-major [2][NN][32] ----
__global__ __launch_bounds__(256) void gemm2_k(
    const u16* __restrict__ Ab, const u16* __restrict__ Wt, u16* __restrict__ C,
    float* __restrict__ a_s, float* __restrict__ a_d) {
    gemm_body<128, 64, 1, false, true, true>(blockIdx.x, nullptr, Ab, Wt, C, a_s, a_d);
}

// ---- per-bucket fine CSR, QUARTER-SPLIT: 4 blocks/bucket (784 blocks) ----
// Each block reads the whole bucket (coalesced, L2) but histograms/sorts only
// its 64-node quarter: per-block LDS atomics /4, grid covers all CUs 3x.
// Quarter base offsets from register-counted quarter totals (4 atomics/wave).
// Output (row_ptr, csr_src) is bit-identical to the monolithic version.
__global__ __launch_bounds__(1024) void bucket_csr_k(const unsigned* __restrict__ bbuf,
                                                     const int* __restrict__ gcursor,
                                                     int* __restrict__ row_ptr,
                                                     u16* __restrict__ csr_src) {
    __shared__ int bsc[256];
    __shared__ int hist[64], scn[64], cur[64];
    __shared__ int qcnt[QS];
    __shared__ int se0, scnt, stot;
    __shared__ u16 srt[QCAP];
    int blk = blockIdx.x, b = blk >> 2, q = blk & 3, t = threadIdx.x;
    int v = 0;
    if (t < 256) {
        v = (t < NBKT) ? min(gcursor[t], BCAP) : 0;
        bsc[t] = v;
    }
    if (t < 64) hist[t] = 0;
    if (t < QS) qcnt[t] = 0;
    __syncthreads();
    for (int off = 1; off < 256; off <<= 1) {
        int x = (t < 256 && t >= off) ? bsc[t - off] : 0;
        __syncthreads();
        if (t < 256) bsc[t] += x;
        __syncthreads();
    }
    if (t == b) { se0 = bsc[t] - v; scnt = v; }
    if (t == NBKT - 1) stot = bsc[t];
    __syncthreads();
    int cnt = scnt;
    const unsigned* bb = bbuf + (size_t)b * BCAP;
    // pass 1: per-quarter counts (registers) + my-quarter per-node histogram
    int c0 = 0, c1 = 0, c2 = 0, c3 = 0;
    for (int e = t; e < cnt; e += 1024) {
        unsigned p = bb[e];
        int loc = p & 255;
        int qq = loc >> 6;
        c0 += (qq == 0); c1 += (qq == 1); c2 += (qq == 2); c3 += (qq == 3);
        if (qq == q) atomicAdd(&hist[loc & 63], 1);
    }
#pragma unroll
    for (int off = 32; off; off >>= 1) {
        c0 += __shfl_xor(c0, off); c1 += __shfl_xor(c1, off);
        c2 += __shfl_xor(c2, off); c3 += __shfl_xor(c3, off);
    }
    if ((t & 63) == 0) {
        if (c0) atomicAdd(&qcnt[0], c0);
        if (c1) atomicAdd(&qcnt[1], c1);
        if (c2) atomicAdd(&qcnt[2], c2);
        if (c3) atomicAdd(&qcnt[3], c3);
    }
    __syncthreads();
    int e0q = se0 + (q > 0 ? qcnt[0] : 0) + (q > 1 ? qcnt[1] : 0) +
              (q > 2 ? qcnt[2] : 0);
    int myc = qcnt[q];
    // exclusive scan of my quarter's 64-node histogram
    int hv = 0;
    if (t < 64) { hv = hist[t]; scn[t] = hv; }
    __syncthreads();
    for (int off = 1; off < 64; off <<= 1) {
        int x = (t < 64 && t >= off) ? scn[t - off] : 0;
        __syncthreads();
        if (t < 64) scn[t] += x;
        __syncthreads();
    }
    if (t < 64) {
        int ex = scn[t] - hv;  // exclusive within quarter (LOCAL offset)
        int n = b * 256 + q * 64 + t;
        if (n < NN) row_ptr[n] = e0q + ex;
        cur[t] = ex;
    }
    __syncthreads();
    // pass 2: sort my quarter's edges into LDS, write csr_src coalesced
    for (int e = t; e < cnt; e += 1024) {
        unsigned p = bb[e];
        int loc = p & 255;
        if ((loc >> 6) == q) {
            int pos = atomicAdd(&cur[loc & 63], 1);
            if (pos < QCAP) srt[pos] = (u16)(p >> 8);
        }
    }
    __syncthreads();
    int wn = min(myc, QCAP);
    for (int e = t; e < wn; e += 1024)
        csr_src[e0q + e] = srt[e];
    if (blk == 0 && t == 0) row_ptr[NN] = stot;
}

// ---- layer-1 fused gather (roofline-verified 64us): one WAVE per node ----
template <int CH, int H, bool HEAD>
__global__ __launch_bounds__(256) void gat_gather_k(
    const int* __restrict__ row_ptr, const u16* __restrict__ csr_src,
    const float* __restrict__ a_s, const float* __restrict__ a_d,
    const u16* __restrict__ h, const float* __restrict__ bias,
    u16* __restrict__ outg, const float* __restrict__ Wl,
    const float* __restrict__ bl, float* __restrict__ outh) {
    constexpr int VEC = CH / 64;
    constexpr int JB = 16;
    int n = (blockIdx.x * blockDim.x + threadIdx.x) >> 6;  // global wave id = node
    int lane = threadIdx.x & 63;
    if (n >= NN) return;  // wave-uniform exit
    int r0 = row_ptr[n], r1 = row_ptr[n + 1];
    const bool hi = (VEC == 2) ? (lane >= 32) : false;
    const int shl16 = hi ? 0 : 16;  // select my head's bf16 ex into bits 31..16

    float adn0, adn1 = 0.f;
    if (H == 2) {
        float2 adv = *(const float2*)(a_d + n * 2);
        adn0 = adv.x; adn1 = adv.y;
    } else {
        adn0 = a_d[n];
    }

    float dh0 = 0.f, dh1 = 0.f;
    float acc[VEC];
#pragma unroll
    for (int v = 0; v < VEC; ++v) acc[v] = 0.f;

    for (int base = r0; base < r1; base += 64) {
        int cnt = min(64, r1 - base);
        int idx = base + lane;
        bool act = idx < r1;
        int sl = act ? (int)csr_src[idx] : 0;
        unsigned pex;   // H==2: bf16(ex0)|bf16(ex1)<<16 ; H==1: s|bf16(ex)<<16
        if (H == 2) {
            float2 av = *(const float2*)(a_s + sl * 2);
            float e0 = av.x + adn0;
            e0 = e0 > 0.f ? e0 : 0.2f * e0;
            e0 = fminf(e0, 60.f);
            float ex0 = act ? __expf(e0) : 0.f;
            dh0 += ex0;
            float e1 = av.y + adn1;
            e1 = e1 > 0.f ? e1 : 0.2f * e1;
            e1 = fminf(e1, 60.f);
            float ex1 = act ? __expf(e1) : 0.f;
            dh1 += ex1;
            pex = (unsigned)f2b(ex0) | ((unsigned)f2b(ex1) << 16);
        } else {
            float e0 = a_s[sl] + adn0;
            e0 = e0 > 0.f ? e0 : 0.2f * e0;
            e0 = fminf(e0, 60.f);
            float ex0 = act ? __expf(e0) : 0.f;
            dh0 += ex0;
            pex = (unsigned)sl | ((unsigned)f2b(ex0) << 16);
        }
        for (int j0 = 0; j0 < cnt; j0 += JB) {
            if (VEC == 2) {
                int ssu[JB];
                unsigned peu[JB];
#pragma unroll
                for (int i = 0; i < JB; ++i) {
                    ssu[i] = __builtin_amdgcn_readlane(sl, j0 + i);
                    peu[i] = (unsigned)__builtin_amdgcn_readlane((int)pex, j0 + i);
                }
                unsigned hv[JB];
#pragma unroll
                for (int i = 0; i < JB; ++i)
                    hv[i] = ((const unsigned*)(h + (size_t)ssu[i] * CH))[lane];
#pragma unroll
                for (int i = 0; i < JB; ++i) {
                    float exv = __uint_as_float((peu[i] << shl16) & 0xFFFF0000u);
                    acc[0] += exv * __uint_as_float(hv[i] << 16);
                    acc[1] += exv * __uint_as_float(hv[i] & 0xFFFF0000u);
                }
            } else {
                unsigned peu[JB];
#pragma unroll
                for (int i = 0; i < JB; ++i)
                    peu[i] = (unsigned)__builtin_amdgcn_readlane((int)pex, j0 + i);
                u16 hv[JB];
#pragma unroll
                for (int i = 0; i < JB; ++i)
                    hv[i] = (h + (size_t)(peu[i] & 0xFFFFu) * CH)[lane];
#pragma unroll
                for (int i = 0; i < JB; ++i)
                    acc[0] += __uint_as_float(peu[i] & 0xFFFF0000u) * b2f(hv[i]);
            }
        }
    }

#pragma unroll
    for (int off = 32; off; off >>= 1) dh0 += __shfl_xor(dh0, off);
    float dn = dh0;
    if (H == 2) {
#pragma unroll
        for (int off = 32; off; off >>= 1) dh1 += __shfl_xor(dh1, off);
        dn = hi ? dh1 : dh0;
    }

    if (VEC == 2) {
        int c = lane * 2;
        float2 bv = *(const float2*)(bias + c);
        float v0 = acc[0] / dn + bv.x;
        float v1 = acc[1] / dn + bv.y;
        v0 = v0 > 0.f ? v0 : expm1f(v0);
        v1 = v1 > 0.f ? v1 : expm1f(v1);
        ushort2 ov;
        ov.x = f2b(v0); ov.y = f2b(v1);
        // slice-major store: slice = c>>5, offset within = c&31
        *(ushort2*)(outg + (size_t)(c >> 5) * (NN * 32) + (size_t)n * 32 + (c & 31)) = ov;
    } else {
        float v0 = acc[0] / dn + bias[lane];
        v0 = v0 > 0.f ? v0 : expm1f(v0);
        outg[(size_t)n * CH + lane] = f2b(v0);
    }
}

// ---- per-edge alpha precompute for layer 2: A2[e] = src | bf16(ex)<<16 ----
__global__ __launch_bounds__(256) void edge_alpha_k(
    const int* __restrict__ row_ptr, const u16* __restrict__ csr_src,
    const float* __restrict__ a_s, const float* __restrict__ a_d,
    unsigned* __restrict__ A2, float* __restrict__ dninv) {
    int wave = threadIdx.x >> 6;
    int pair = blockIdx.x * 4 + wave;
    if (pair >= NN / 2) return;
    int lane = threadIdx.x & 63, half = lane >> 5, hl = lane & 31;
    int node = pair * 2 + half;
    int r0 = row_ptr[node], r1 = row_ptr[node + 1];
    int cnt = r1 - r0;
    int co = max(cnt, __shfl_xor(cnt, 32));
    int nbat = (co + 31) >> 5;
    float adn = a_d[node];
    float dh = 0.f;
    for (int b = 0; b < nbat; ++b) {
        int idx = r0 + b * 32 + hl;
        bool act = idx < r1;
        int sl = act ? (int)csr_src[idx] : 0;
        float e = a_s[sl] + adn;
        e = e > 0.f ? e : 0.2f * e;
        e = fminf(e, 60.f);
        float ex = act ? __expf(e) : 0.f;
        dh += ex;
        if (act)
            __builtin_nontemporal_store(
                (unsigned)sl | ((unsigned)f2b(ex) << 16), A2 + idx);
    }
#pragma unroll
    for (int off = 1; off < 32; off <<= 1) dh += __shfl_xor(dh, off);
    if (hl == 0) dninv[node] = 1.0f / dh;
}

// ---- layer-2 slice gather with XCD-L2 affinity (USE_EX) ----
template <int CH, int NSL, int H, bool USE_EX>
__global__ __launch_bounds__(256) void gat_slice_k(
    const int* __restrict__ row_ptr, const u16* __restrict__ csr_src,
    const unsigned* __restrict__ A2, const float* __restrict__ a_s,
    const float* __restrict__ a_d, const float* __restrict__ dninv,
    const u16* __restrict__ h, const float* __restrict__ bias,
    u16* __restrict__ outg) {
    constexpr int SC = CH / NSL;   // 32 channels (64 B) per slice
    constexpr int SUB = 8 / NSL;   // XCDs per slice
    int xcd = blockIdx.x & 7;
    int slice = xcd / SUB;
    int sub = xcd % SUB;
    int pg = (blockIdx.x >> 3) * SUB + sub;
    int wave = threadIdx.x >> 6;
    int pair = pg * 4 + wave;
    if (pair >= NN / 2) return;  // wave-uniform
    int lane = threadIdx.x & 63;
    int half = lane >> 5, hl = lane & 31, q = hl & 7, gh = hl >> 3;
    int node = pair * 2 + half;
    int r0 = row_ptr[node], r1 = row_ptr[node + 1];
    int cnt = r1 - r0;
    int co = max(cnt, __shfl_xor(cnt, 32));
    int nbat = (co + 31) >> 5;
    const unsigned char* hb8 =
        (const unsigned char*)h + (size_t)slice * (NN * 64);
    const int head = (H == 2) ? (slice >> 1) : 0;
    float adn = 0.f, rdn = 0.f;
    if constexpr (USE_EX) rdn = dninv[node];
    else adn = a_d[node * H + head];
    float dh = 0.f;
    float acc[4] = {0.f, 0.f, 0.f, 0.f};
    const int abase = ((half << 5) | gh) << 2;
    for (int b = 0; b < nbat; ++b) {
        int idx = r0 + b * 32 + hl;
        bool act = idx < r1;
        unsigned pex;
        if constexpr (USE_EX) {
            pex = act ? __builtin_nontemporal_load(A2 + idx) : 0u;
        } else {
            int sl = act ? (int)__builtin_nontemporal_load(csr_src + idx) : 0;
            float e = a_s[sl * H + head] + adn;
            e = e > 0.f ? e : 0.2f * e;
            e = fminf(e, 60.f);
            float ex = act ? __expf(e) : 0.f;
            dh += ex;
            pex = (unsigned)sl | ((unsigned)f2b(ex) << 16);
        }
#pragma unroll
        for (int jr = 0; jr < 2; ++jr) {
            int pr[4];
#pragma unroll
            for (int i = 0; i < 4; ++i)
                pr[i] = __builtin_amdgcn_ds_bpermute(
                    abase + ((jr * 16 + i * 4) << 2), (int)pex);
            unsigned hv0[4], hv1[4];
#pragma unroll
            for (int i = 0; i < 4; ++i) {
                const unsigned* p = (const unsigned*)(
                    hb8 + (((unsigned)((unsigned)pr[i] & 0xFFFFu) << 6) + q * 8));
                hv0[i] = p[0];
                hv1[i] = p[1];
            }
#pragma unroll
            for (int i = 0; i < 4; ++i) {
                float exf = __uint_as_float((unsigned)pr[i] & 0xFFFF0000u);
                unsigned w0 = hv0[i], w1 = hv1[i];
                acc[0] += exf * __uint_as_float(w0 << 16);
                acc[1] += exf * __uint_as_float(w0 & 0xFFFF0000u);
                acc[2] += exf * __uint_as_float(w1 << 16);
                acc[3] += exf * __uint_as_float(w1 & 0xFFFF0000u);
            }
        }
    }
    if constexpr (!USE_EX) {
#pragma unroll
        for (int off = 1; off < 32; off <<= 1) dh += __shfl_xor(dh, off);
        rdn = 1.0f / dh;
    }
#pragma unroll
    for (int v = 0; v < 4; ++v) {
        acc[v] += __shfl_xor(acc[v], 8);
        acc[v] += __shfl_xor(acc[v], 16);
    }
    if (gh == 0) {
        float vv[4];
#pragma unroll
        for (int k = 0; k < 4; ++k) {
            float t = acc[k] * rdn + bias[slice * SC + q * 4 + k];
            vv[k] = t > 0.f ? t : expm1f(t);
        }
        unsigned long long ov =
            (unsigned long long)((unsigned)f2b(vv[0]) | ((unsigned)f2b(vv[1]) << 16)) |
            ((unsigned long long)((unsigned)f2b(vv[2]) | ((unsigned)f2b(vv[3]) << 16)) << 32);
        __builtin_nontemporal_store(
            ov, (unsigned long long*)(outg + (size_t)slice * (NN * 32) +
                                      (size_t)node * 32 + q * 4));
    }
}

// ---- head: out[NN][10] = g2[NN][64] (sliced bf16) @ Wl + bl via MFMA ----
__global__ __launch_bounds__(256) void head_gemm_k(
    const u16* __restrict__ A, const u16* __restrict__ Wt,
    const float* __restrict__ bl, float* __restrict__ out) {
    const int wave = threadIdx.x >> 6, lane = threadIdx.x & 63;
    const int quad = lane >> 4, l15 = lane & 15;
    const int m0 = blockIdx.x * 64 + wave * 16;
    int rowA = m0 + l15;
    if (rowA >= NN) rowA = NN - 1;
    const u16* ab = A + (size_t)rowA * 32 + quad * 8;
    const u16* bp = Wt + (size_t)l15 * 64 + quad * 8;
    f32x4 acc = {};
#pragma unroll
    for (int ks = 0; ks < 2; ++ks) {
        bf16x8 af = *(const bf16x8*)(ab + (size_t)ks * (NN * 32));
        bf16x8 bf = *(const bf16x8*)(bp + ks * 32);
        acc = __builtin_amdgcn_mfma_f32_16x16x32_bf16(af, bf, acc, 0, 0, 0);
    }
    if (l15 < NCLS) {
        float blv = bl[l15];
#pragma unroll
        for (int reg = 0; reg < 4; ++reg) {
            int row = m0 + quad * 4 + reg;
            if (row < NN) out[(size_t)row * NCLS + l15] = acc[reg] + blv;
        }
    }
}

extern "C" void kernel_launch(void* const* d_in, const int* in_sizes, int n_in,
                              void* d_out, int out_size, void* d_ws, size_t ws_size,
                              hipStream_t stream) {
    const float* x   = (const float*)d_in[0];
    const int*   ei  = (const int*)d_in[1];
    const float* W1  = (const float*)d_in[2];
    const float* as1 = (const float*)d_in[3];
    const float* ad1 = (const float*)d_in[4];
    const float* b1  = (const float*)d_in[5];
    const float* W2  = (const float*)d_in[6];
    const float* as2 = (const float*)d_in[7];
    const float* ad2 = (const float*)d_in[8];
    const float* b2  = (const float*)d_in[9];
    const float* Wl  = (const float*)d_in[10];
    const float* bl  = (const float*)d_in[11];
    float* out = (float*)d_out;

    // ---- workspace layout (~30 MB) ----
    float* ws = (float*)d_ws;
    size_t o = 0;
    u16* hb  = (u16*)(ws + o); o += (size_t)NN * 64;  // h1 [NN][128] row-major / h2 [2][NN][32] + g2
    u16* g2  = hb + (size_t)NN * 64;                  // g2 [2][NN][32] (upper half of hb)
    u16* g1  = (u16*)(ws + o); o += (size_t)NN * 64;  // g1 [4][NN][32]; bbuf overlay; A2 overlay
    unsigned* bbuf = (unsigned*)g1;                   // 9.63 MB <= 12.8 MB (until bucket_csr)
    unsigned* A2 = (unsigned*)g1;                     // 6.6 MB (after gemm2 consumed g1)
    float* dn2inv = (float*)((char*)g1 + (size_t)EP * 4);  // +200 KB, still in g1
    u16* w1t = (u16*)(ws + o); o += 144 * 256 / 2;    // bf16 W1^T+att [144][256]
    u16* w2t = (u16*)(ws + o); o += 80 * 128 / 2;     // bf16 W2^T+att [80][128]
    u16* wlt = (u16*)(ws + o); o += 16 * 64 / 2;      // bf16 Wl^T padded [16][64]
    float* a_s = ws + o;       o += (size_t)NN * 2;
    float* a_d = ws + o;       o += (size_t)NN * 2;
    int* ints = (int*)(ws + o);
    size_t io = 0;
    int* gcursor  = ints + io; io += NBKT;
    int* row_ptr  = ints + io; io += NN + 1;
    u16* csr_src  = (u16*)(ints + io); io += (EP + 1) / 2;

    const int gemmBlocks = (NN + 63) / 64;  // 782
    const int gatherBlocks = (NN + 3) / 4;  // 4 waves (nodes) per 256-thread block

    // K0: weight conversion + Wl transpose + gcursor zero
    wcvt_k<<<189, 256, 0, stream>>>(W1, as1, ad1, w1t, W2, as2, ad2, w2t,
                                    Wl, wlt, gcursor);
    // K1: partition (blocks 0..805) || layer-1 GEMM (blocks 806..1587)
    part_gemm_k<<<NPB + gemmBlocks, 256, 0, stream>>>(
        ei, gcursor, bbuf, x, w1t, hb, a_s, a_d);
    // K2: per-bucket fine CSR, quarter-split (4 blocks/bucket)
    bucket_csr_k<<<NBKT * QS, 1024, 0, stream>>>(bbuf, gcursor, row_ptr, csr_src);
    // K3: layer-1 gather + ELU (writes g1 slice-major)
    gat_gather_k<128, 2, false><<<gatherBlocks, 256, 0, stream>>>(
        row_ptr, csr_src, a_s, a_d, hb, b1, g1, nullptr, nullptr, nullptr);
    // K4: layer-2 GEMM (sliced A, sliced h2 out)
    gemm2_k<<<gemmBlocks, 256, 0, stream>>>(g1, w2t, hb, a_s, a_d);
    // K5: layer-2 per-edge alpha (A2 overlays g1, now dead)
    edge_alpha_k<<<(NN / 2 + 3) / 4, 256, 0, stream>>>(
        row_ptr, csr_src, a_s, a_d, A2, dn2inv);
    // K6: layer-2 slice gather (2 slices x 4 XCDs)
    gat_slice_k<64, 2, 1, true><<<12504, 256, 0, stream>>>(
        row_ptr, csr_src, A2, nullptr, nullptr, dn2inv, hb, b2, g2);
    // K7: fused head
    head_gemm_k<<<gemmBlocks, 256, 0, stream>>>(g2, wlt, bl, out);
}

// Round 12
// 303.076 us; speedup vs baseline: 1.0558x; 1.0526x over previous
//
#include <hip/hip_runtime.h>

#define NN 50000
#define NE 1600000
#define EP (NE + NN)   // edges + self loops
#define IN_DIM 256
#define HIDD 64
#define NCLS 10
#define NBKT 196                       // destination buckets: d >> 8
#define EPB 8192                       // edges per partition block
#define NPB ((EP + EPB - 1) / EPB)     // 202 partition blocks
#define BCAP 12288                     // fixed bucket capacity (exp 8418 +- 92)

typedef unsigned short u16;
typedef short bf16x8 __attribute__((ext_vector_type(8)));
typedef float f32x4 __attribute__((ext_vector_type(4)));

__device__ __forceinline__ float b2f(u16 v) { return __uint_as_float(((unsigned)v) << 16); }
__device__ __forceinline__ u16 f2b(float f) {
    unsigned u = __float_as_uint(f);
    unsigned r = (u + 0x7FFFu + ((u >> 16) & 1u)) >> 16;
    return (u16)r;
}

__device__ __forceinline__ void load_edge(const int* __restrict__ ei, int m, int g,
                                          int& s, int& d) {
    if (g < NE) {
        if (m) { s = ei[2 * (size_t)g]; d = ei[2 * ((size_t)NE + g)]; }
        else   { s = ei[g];             d = ei[NE + g]; }
    } else {
        s = d = g - NE;  // self loop
    }
    s = s < 0 ? 0 : (s >= NN ? NN - 1 : s);
    d = d < 0 ? 0 : (d >= NN ? NN - 1 : d);
}

// ---- weight transpose + augmented score rows (device helper) ----
__device__ __forceinline__ void wcvt_att_job(
    const float* __restrict__ W, const float* __restrict__ as,
    const float* __restrict__ ad, int K, int N, int H, u16* __restrict__ Wt,
    int idx) {
    if (idx >= K * (N + 16)) return;
    int n = idx / K, k = idx - n * K;
    if (n < N) { Wt[idx] = f2b(W[(size_t)k * N + n]); return; }
    int j = n - N;
    if (j >= 2 * H) { Wt[idx] = 0; return; }
    const float* att = (j & 1) ? ad : as;
    int h = j >> 1, C = N / H;
    float sum = 0.f;
    for (int c = 0; c < C; ++c)
        sum += W[(size_t)k * N + h * C + c] * att[h * C + c];
    Wt[idx] = f2b(sum);
}

// ---- partition pass: LDS counting-sort per block -> COALESCED bbuf writes ----
__global__ __launch_bounds__(1024) void partition_k(
    const int* __restrict__ ei, int* __restrict__ gcursor,
    unsigned* __restrict__ bbuf,
    const float* __restrict__ W1, const float* __restrict__ as1,
    const float* __restrict__ ad1, u16* __restrict__ w1t,
    const float* __restrict__ W2, const float* __restrict__ as2,
    const float* __restrict__ ad2, u16* __restrict__ w2t,
    const float* __restrict__ Wl, u16* __restrict__ wlt) {
    __shared__ int hist[NBKT], base[NBKT], lbase[NBKT], lcur[NBKT];
    __shared__ int psc[256];
    __shared__ unsigned sst[EPB];
    __shared__ int smode;
    int t = threadIdx.x, b = blockIdx.x;
    // side jobs: W1 on blocks 0..35, W2 on 36..45, Wl transpose on 46
    if (b < 36) wcvt_att_job(W1, as1, ad1, 256, 128, 2, w1t, b * 1024 + t);
    else if (b < 46) wcvt_att_job(W2, as2, ad2, 128, 64, 1, w2t, (b - 36) * 1024 + t);
    else if (b == 46) {
        int n = t >> 6, k = t & 63;  // wlt[16][64] = Wl^T padded
        wlt[n * 64 + k] = (n < NCLS) ? f2b(Wl[k * NCLS + n]) : (u16)0;
    }
    // local dtype detect (wave 0)
    if (t < 64) {
        int nz = 0;
#pragma unroll
        for (int k = 0; k < 4; ++k)
            if (ei[2 * (t * 4 + k) + 1] != 0) nz = 1;
        unsigned long long bal = __ballot(nz);
        if (t == 0) smode = (bal == 0ULL) ? 1 : 0;  // 1 = int64 layout
    }
    for (int i = t; i < NBKT; i += 1024) hist[i] = 0;
    __syncthreads();
    int m = smode;
    int g0 = b * EPB;
    int gend = min(g0 + EPB, EP);
    // pass A: histogram
    for (int g = g0 + t; g < gend; g += 1024) {
        int s, d;
        load_edge(ei, m, g, s, d);
        atomicAdd(&hist[d >> 8], 1);
    }
    __syncthreads();
    // exclusive scan of hist -> lbase; claim global bucket ranges -> base
    int hv = 0;
    if (t < 256) { hv = (t < NBKT) ? hist[t] : 0; psc[t] = hv; }
    __syncthreads();
    for (int off = 1; off < 256; off <<= 1) {
        int x = (t < 256 && t >= off) ? psc[t - off] : 0;
        __syncthreads();
        if (t < 256) psc[t] += x;
        __syncthreads();
    }
    if (t < NBKT) {
        lbase[t] = psc[t] - hv;
        lcur[t] = 0;
        base[t] = hv ? atomicAdd(&gcursor[t], hv) : 0;
    }
    __syncthreads();
    // pass B: re-read edges, scatter into LDS sorted-by-bucket order
    for (int g = g0 + t; g < gend; g += 1024) {
        int s, d;
        load_edge(ei, m, g, s, d);
        unsigned p = ((unsigned)s << 16) | (unsigned)d;
        int bb = d >> 8;
        int r = lbase[bb] + atomicAdd(&lcur[bb], 1);
        sst[r] = p;
    }
    __syncthreads();
    // pass C: coalesced global write (consecutive l in same bucket)
    int cnt = gend - g0;
    for (int l = t; l < cnt; l += 1024) {
        unsigned p = sst[l];
        int bb = (p & 0xFFFF) >> 8;
        int gp = base[bb] + (l - lbase[bb]);
        if (gp < BCAP)  // harden: adversarial skew can't write OOB
            bbuf[(size_t)bb * BCAP + gp] = ((p >> 16) << 8) | (p & 255u);
    }
}

// ---- per-bucket fine CSR; LDS sort -> COALESCED csr_src writes ----
__global__ __launch_bounds__(1024) void bucket_csr_k(const unsigned* __restrict__ bbuf,
                                                     const int* __restrict__ gcursor,
                                                     int* __restrict__ row_ptr,
                                                     u16* __restrict__ csr_src) {
    __shared__ int bsc[256];
    __shared__ int hist[256], scn[256], cur[256];
    __shared__ int se0, scnt, stot;
    __shared__ u16 srt[BCAP];
    int b = blockIdx.x, t = threadIdx.x;
    int v = 0;
    if (t < 256) {
        v = (t < NBKT) ? min(gcursor[t], BCAP) : 0;
        bsc[t] = v;
        hist[t] = 0;
    }
    __syncthreads();
    for (int off = 1; off < 256; off <<= 1) {
        int x = (t < 256 && t >= off) ? bsc[t - off] : 0;
        __syncthreads();
        if (t < 256) bsc[t] += x;
        __syncthreads();
    }
    if (t == b) { se0 = bsc[t] - v; scnt = v; }
    if (t == NBKT - 1) stot = bsc[t];
    __syncthreads();
    int e0 = se0, cnt = scnt;
    const unsigned* bb = bbuf + (size_t)b * BCAP;
    for (int e = t; e < cnt; e += 1024)
        atomicAdd(&hist[bb[e] & 255], 1);
    __syncthreads();
    int hv = 0;
    if (t < 256) { hv = hist[t]; scn[t] = hv; }
    __syncthreads();
    for (int off = 1; off < 256; off <<= 1) {
        int x = (t < 256 && t >= off) ? scn[t - off] : 0;
        __syncthreads();
        if (t < 256) scn[t] += x;
        __syncthreads();
    }
    if (t < 256) {
        int ex = scn[t] - hv;  // exclusive within bucket (LOCAL offset)
        int n = b * 256 + t;
        if (n < NN) row_ptr[n] = e0 + ex;
        cur[t] = ex;
    }
    __syncthreads();
    // sort into LDS by node, then write csr_src coalesced
    for (int e = t; e < cnt; e += 1024) {
        unsigned p = bb[e];
        int pos = atomicAdd(&cur[p & 255], 1);
        srt[pos] = (u16)(p >> 8);
    }
    __syncthreads();
    for (int e = t; e < cnt; e += 1024)
        csr_src[e0 + e] = srt[e];
    if (b == 0 && t == 0) row_ptr[NN] = stot;
}

// ---- MFMA GEMM + fused scores; C row-major or slice-major [NF/32][NN][32] ----
template <int K, int NF, int H, bool F32A, bool SLICED_A, bool SLICED_C>
__global__ __launch_bounds__(256) void gemm_mfma_att_k(
    const float* __restrict__ Af, const u16* __restrict__ Ab,
    const u16* __restrict__ Wt, u16* __restrict__ C,
    float* __restrict__ a_s, float* __restrict__ a_d) {
    constexpr int NTF = NF / 16, NT = NTF + 1, KS = K / 32;
    const int wave = threadIdx.x >> 6, lane = threadIdx.x & 63;
    const int quad = lane >> 4, l15 = lane & 15;
    const int m0 = blockIdx.x * 64 + wave * 16;
    int rowA = m0 + l15;
    if (rowA >= NN) rowA = NN - 1;
    const float* afp = F32A ? (Af + (size_t)rowA * K + quad * 8) : nullptr;
    const u16* abp = nullptr;
    if constexpr (!F32A) {
        abp = SLICED_A ? (Ab + (size_t)rowA * 32 + quad * 8)
                       : (Ab + (size_t)rowA * K + quad * 8);
    }
    const u16* bptr = Wt + (size_t)l15 * K + quad * 8;
    f32x4 acc[NT] = {};
#pragma unroll
    for (int ks = 0; ks < KS; ++ks) {
        bf16x8 af;
        if constexpr (F32A) {
            float4 v0 = *(const float4*)(afp + ks * 32);
            float4 v1 = *(const float4*)(afp + ks * 32 + 4);
            af[0] = (short)f2b(v0.x); af[1] = (short)f2b(v0.y);
            af[2] = (short)f2b(v0.z); af[3] = (short)f2b(v0.w);
            af[4] = (short)f2b(v1.x); af[5] = (short)f2b(v1.y);
            af[6] = (short)f2b(v1.z); af[7] = (short)f2b(v1.w);
        } else {
            af = SLICED_A ? *(const bf16x8*)(abp + (size_t)ks * (NN * 32))
                          : *(const bf16x8*)(abp + ks * 32);
        }
        bf16x8 bf[NT];
#pragma unroll
        for (int nt = 0; nt < NT; ++nt)
            bf[nt] = *(const bf16x8*)(bptr + (size_t)nt * 16 * K + ks * 32);
#pragma unroll
        for (int nt = 0; nt < NT; ++nt)
            acc[nt] = __builtin_amdgcn_mfma_f32_16x16x32_bf16(af, bf[nt], acc[nt], 0, 0, 0);
    }
#pragma unroll
    for (int nt = 0; nt < NTF; ++nt) {
#pragma unroll
        for (int reg = 0; reg < 4; ++reg) {
            int row = m0 + quad * 4 + reg;
            int c = nt * 16 + l15;
            if (row < NN) {
                if constexpr (SLICED_C)
                    C[(size_t)(c >> 5) * (NN * 32) + (size_t)row * 32 + (c & 31)] =
                        f2b(acc[nt][reg]);
                else
                    C[(size_t)row * NF + c] = f2b(acc[nt][reg]);
            }
        }
    }
    if (l15 < 2 * H) {
        int h = l15 >> 1;
        float* dst = (l15 & 1) ? a_d : a_s;
#pragma unroll
        for (int reg = 0; reg < 4; ++reg) {
            int row = m0 + quad * 4 + reg;
            if (row < NN) dst[row * H + h] = acc[NTF][reg];
        }
    }
}

// ---- layer-1 fused gather (roofline-verified 64us): one WAVE per node ----
// Full 256B h-row per edge via 64x4B lanes; JB=16 readlane broadcast.
// Output store is SLICE-MAJOR [4][NN][32] for gemm2's SLICED_A path.
template <int CH, int H, bool HEAD>
__global__ __launch_bounds__(256) void gat_gather_k(
    const int* __restrict__ row_ptr, const u16* __restrict__ csr_src,
    const float* __restrict__ a_s, const float* __restrict__ a_d,
    const u16* __restrict__ h, const float* __restrict__ bias,
    u16* __restrict__ outg, const float* __restrict__ Wl,
    const float* __restrict__ bl, float* __restrict__ outh) {
    constexpr int VEC = CH / 64;
    constexpr int JB = 16;
    int n = (blockIdx.x * blockDim.x + threadIdx.x) >> 6;  // global wave id = node
    int lane = threadIdx.x & 63;
    if (n >= NN) return;  // wave-uniform exit
    int r0 = row_ptr[n], r1 = row_ptr[n + 1];
    const bool hi = (VEC == 2) ? (lane >= 32) : false;
    const int shl16 = hi ? 0 : 16;  // select my head's bf16 ex into bits 31..16

    float adn0, adn1 = 0.f;
    if (H == 2) {
        float2 adv = *(const float2*)(a_d + n * 2);
        adn0 = adv.x; adn1 = adv.y;
    } else {
        adn0 = a_d[n];
    }

    float dh0 = 0.f, dh1 = 0.f;
    float acc[VEC];
#pragma unroll
    for (int v = 0; v < VEC; ++v) acc[v] = 0.f;

    for (int base = r0; base < r1; base += 64) {
        int cnt = min(64, r1 - base);
        int idx = base + lane;
        bool act = idx < r1;
        int sl = act ? (int)csr_src[idx] : 0;
        unsigned pex;   // H==2: bf16(ex0)|bf16(ex1)<<16 ; H==1: s|bf16(ex)<<16
        if (H == 2) {
            float2 av = *(const float2*)(a_s + sl * 2);
            float e0 = av.x + adn0;
            e0 = e0 > 0.f ? e0 : 0.2f * e0;
            e0 = fminf(e0, 60.f);
            float ex0 = act ? __expf(e0) : 0.f;
            dh0 += ex0;
            float e1 = av.y + adn1;
            e1 = e1 > 0.f ? e1 : 0.2f * e1;
            e1 = fminf(e1, 60.f);
            float ex1 = act ? __expf(e1) : 0.f;
            dh1 += ex1;
            pex = (unsigned)f2b(ex0) | ((unsigned)f2b(ex1) << 16);
        } else {
            float e0 = a_s[sl] + adn0;
            e0 = e0 > 0.f ? e0 : 0.2f * e0;
            e0 = fminf(e0, 60.f);
            float ex0 = act ? __expf(e0) : 0.f;
            dh0 += ex0;
            pex = (unsigned)sl | ((unsigned)f2b(ex0) << 16);
        }
        for (int j0 = 0; j0 < cnt; j0 += JB) {
            if (VEC == 2) {
                int ssu[JB];
                unsigned peu[JB];
#pragma unroll
                for (int i = 0; i < JB; ++i) {
                    ssu[i] = __builtin_amdgcn_readlane(sl, j0 + i);
                    peu[i] = (unsigned)__builtin_amdgcn_readlane((int)pex, j0 + i);
                }
                unsigned hv[JB];
#pragma unroll
                for (int i = 0; i < JB; ++i)
                    hv[i] = ((const unsigned*)(h + (size_t)ssu[i] * CH))[lane];
#pragma unroll
                for (int i = 0; i < JB; ++i) {
                    float exv = __uint_as_float((peu[i] << shl16) & 0xFFFF0000u);
                    acc[0] += exv * __uint_as_float(hv[i] << 16);
                    acc[1] += exv * __uint_as_float(hv[i] & 0xFFFF0000u);
                }
            } else {
                unsigned peu[JB];
#pragma unroll
                for (int i = 0; i < JB; ++i)
                    peu[i] = (unsigned)__builtin_amdgcn_readlane((int)pex, j0 + i);
                u16 hv[JB];
#pragma unroll
                for (int i = 0; i < JB; ++i)
                    hv[i] = (h + (size_t)(peu[i] & 0xFFFFu) * CH)[lane];
#pragma unroll
                for (int i = 0; i < JB; ++i)
                    acc[0] += __uint_as_float(peu[i] & 0xFFFF0000u) * b2f(hv[i]);
            }
        }
    }

#pragma unroll
    for (int off = 32; off; off >>= 1) dh0 += __shfl_xor(dh0, off);
    float dn = dh0;
    if (H == 2) {
#pragma unroll
        for (int off = 32; off; off >>= 1) dh1 += __shfl_xor(dh1, off);
        dn = hi ? dh1 : dh0;
    }

    if (VEC == 2) {
        int c = lane * 2;
        float2 bv = *(const float2*)(bias + c);
        float v0 = acc[0] / dn + bv.x;
        float v1 = acc[1] / dn + bv.y;
        v0 = v0 > 0.f ? v0 : expm1f(v0);
        v1 = v1 > 0.f ? v1 : expm1f(v1);
        ushort2 ov;
        ov.x = f2b(v0); ov.y = f2b(v1);
        // slice-major store: slice = c>>5, offset within = c&31
        *(ushort2*)(outg + (size_t)(c >> 5) * (NN * 32) + (size_t)n * 32 + (c & 31)) = ov;
    } else {
        float v0 = acc[0] / dn + bias[lane];
        v0 = v0 > 0.f ? v0 : expm1f(v0);
        if (HEAD) {
#pragma unroll
            for (int cls = 0; cls < NCLS; ++cls) {
                float p = v0 * Wl[lane * NCLS + cls];
#pragma unroll
                for (int off = 32; off; off >>= 1) p += __shfl_xor(p, off);
                if (lane == cls) outh[(size_t)n * NCLS + cls] = p + bl[cls];
            }
        } else {
            outg[(size_t)n * CH + lane] = f2b(v0);
        }
    }
}

// ---- per-edge alpha precompute for layer 2: A2[e] = src | bf16(ex)<<16 ----
__global__ __launch_bounds__(256) void edge_alpha_k(
    const int* __restrict__ row_ptr, const u16* __restrict__ csr_src,
    const float* __restrict__ a_s, const float* __restrict__ a_d,
    unsigned* __restrict__ A2, float* __restrict__ dninv) {
    int wave = threadIdx.x >> 6;
    int pair = blockIdx.x * 4 + wave;
    if (pair >= NN / 2) return;
    int lane = threadIdx.x & 63, half = lane >> 5, hl = lane & 31;
    int node = pair * 2 + half;
    int r0 = row_ptr[node], r1 = row_ptr[node + 1];
    int cnt = r1 - r0;
    int co = max(cnt, __shfl_xor(cnt, 32));
    int nbat = (co + 31) >> 5;
    float adn = a_d[node];
    float dh = 0.f;
    for (int b = 0; b < nbat; ++b) {
        int idx = r0 + b * 32 + hl;
        bool act = idx < r1;
        int sl = act ? (int)csr_src[idx] : 0;
        float e = a_s[sl] + adn;
        e = e > 0.f ? e : 0.2f * e;
        e = fminf(e, 60.f);
        float ex = act ? __expf(e) : 0.f;
        dh += ex;
        if (act)
            __builtin_nontemporal_store(
                (unsigned)sl | ((unsigned)f2b(ex) << 16), A2 + idx);
    }
#pragma unroll
    for (int off = 1; off < 32; off <<= 1) dh += __shfl_xor(dh, off);
    if (hl == 0) dninv[node] = 1.0f / dh;
}

// ---- layer-2 slice gather with XCD-L2 affinity (USE_EX) ----
template <int CH, int NSL, int H, bool USE_EX>
__global__ __launch_bounds__(256) void gat_slice_k(
    const int* __restrict__ row_ptr, const u16* __restrict__ csr_src,
    const unsigned* __restrict__ A2, const float* __restrict__ a_s,
    const float* __restrict__ a_d, const float* __restrict__ dninv,
    const u16* __restrict__ h, const float* __restrict__ bias,
    u16* __restrict__ outg) {
    constexpr int SC = CH / NSL;   // 32 channels (64 B) per slice
    constexpr int SUB = 8 / NSL;   // XCDs per slice
    int xcd = blockIdx.x & 7;
    int slice = xcd / SUB;
    int sub = xcd % SUB;
    int pg = (blockIdx.x >> 3) * SUB + sub;
    int wave = threadIdx.x >> 6;
    int pair = pg * 4 + wave;
    if (pair >= NN / 2) return;  // wave-uniform
    int lane = threadIdx.x & 63;
    int half = lane >> 5, hl = lane & 31, q = hl & 7, gh = hl >> 3;
    int node = pair * 2 + half;
    int r0 = row_ptr[node], r1 = row_ptr[node + 1];
    int cnt = r1 - r0;
    int co = max(cnt, __shfl_xor(cnt, 32));
    int nbat = (co + 31) >> 5;
    const unsigned char* hb8 =
        (const unsigned char*)h + (size_t)slice * (NN * 64);
    const int head = (H == 2) ? (slice >> 1) : 0;
    float adn = 0.f, rdn = 0.f;
    if constexpr (USE_EX) rdn = dninv[node];
    else adn = a_d[node * H + head];
    float dh = 0.f;
    float acc[4] = {0.f, 0.f, 0.f, 0.f};
    const int abase = ((half << 5) | gh) << 2;
    for (int b = 0; b < nbat; ++b) {
        int idx = r0 + b * 32 + hl;
        bool act = idx < r1;
        unsigned pex;
        if constexpr (USE_EX) {
            pex = act ? __builtin_nontemporal_load(A2 + idx) : 0u;
        } else {
            int sl = act ? (int)__builtin_nontemporal_load(csr_src + idx) : 0;
            float e = a_s[sl * H + head] + adn;
            e = e > 0.f ? e : 0.2f * e;
            e = fminf(e, 60.f);
            float ex = act ? __expf(e) : 0.f;
            dh += ex;
            pex = (unsigned)sl | ((unsigned)f2b(ex) << 16);
        }
#pragma unroll
        for (int jr = 0; jr < 2; ++jr) {
            int pr[4];
#pragma unroll
            for (int i = 0; i < 4; ++i)
                pr[i] = __builtin_amdgcn_ds_bpermute(
                    abase + ((jr * 16 + i * 4) << 2), (int)pex);
            unsigned hv0[4], hv1[4];
#pragma unroll
            for (int i = 0; i < 4; ++i) {
                const unsigned* p = (const unsigned*)(
                    hb8 + (((unsigned)((unsigned)pr[i] & 0xFFFFu) << 6) + q * 8));
                hv0[i] = p[0];
                hv1[i] = p[1];
            }
#pragma unroll
            for (int i = 0; i < 4; ++i) {
                float exf = __uint_as_float((unsigned)pr[i] & 0xFFFF0000u);
                unsigned w0 = hv0[i], w1 = hv1[i];
                acc[0] += exf * __uint_as_float(w0 << 16);
                acc[1] += exf * __uint_as_float(w0 & 0xFFFF0000u);
                acc[2] += exf * __uint_as_float(w1 << 16);
                acc[3] += exf * __uint_as_float(w1 & 0xFFFF0000u);
            }
        }
    }
    if constexpr (!USE_EX) {
#pragma unroll
        for (int off = 1; off < 32; off <<= 1) dh += __shfl_xor(dh, off);
        rdn = 1.0f / dh;
    }
#pragma unroll
    for (int v = 0; v < 4; ++v) {
        acc[v] += __shfl_xor(acc[v], 8);
        acc[v] += __shfl_xor(acc[v], 16);
    }
    if (gh == 0) {
        float vv[4];
#pragma unroll
        for (int k = 0; k < 4; ++k) {
            float t = acc[k] * rdn + bias[slice * SC + q * 4 + k];
            vv[k] = t > 0.f ? t : expm1f(t);
        }
        unsigned long long ov =
            (unsigned long long)((unsigned)f2b(vv[0]) | ((unsigned)f2b(vv[1]) << 16)) |
            ((unsigned long long)((unsigned)f2b(vv[2]) | ((unsigned)f2b(vv[3]) << 16)) << 32);
        __builtin_nontemporal_store(
            ov, (unsigned long long*)(outg + (size_t)slice * (NN * 32) +
                                      (size_t)node * 32 + q * 4));
    }
}

// ---- head: out[NN][10] = g2[NN][64] (sliced bf16) @ Wl + bl via MFMA ----
__global__ __launch_bounds__(256) void head_gemm_k(
    const u16* __restrict__ A, const u16* __restrict__ Wt,
    const float* __restrict__ bl, float* __restrict__ out) {
    const int wave = threadIdx.x >> 6, lane = threadIdx.x & 63;
    const int quad = lane >> 4, l15 = lane & 15;
    const int m0 = blockIdx.x * 64 + wave * 16;
    int rowA = m0 + l15;
    if (rowA >= NN) rowA = NN - 1;
    const u16* ab = A + (size_t)rowA * 32 + quad * 8;
    const u16* bp = Wt + (size_t)l15 * 64 + quad * 8;
    f32x4 acc = {};
#pragma unroll
    for (int ks = 0; ks < 2; ++ks) {
        bf16x8 af = *(const bf16x8*)(ab + (size_t)ks * (NN * 32));
        bf16x8 bf = *(const bf16x8*)(bp + ks * 32);
        acc = __builtin_amdgcn_mfma_f32_16x16x32_bf16(af, bf, acc, 0, 0, 0);
    }
    if (l15 < NCLS) {
        float blv = bl[l15];
#pragma unroll
        for (int reg = 0; reg < 4; ++reg) {
            int row = m0 + quad * 4 + reg;
            if (row < NN) out[(size_t)row * NCLS + l15] = acc[reg] + blv;
        }
    }
}

extern "C" void kernel_launch(void* const* d_in, const int* in_sizes, int n_in,
                              void* d_out, int out_size, void* d_ws, size_t ws_size,
                              hipStream_t stream) {
    const float* x   = (const float*)d_in[0];
    const int*   ei  = (const int*)d_in[1];
    const float* W1  = (const float*)d_in[2];
    const float* as1 = (const float*)d_in[3];
    const float* ad1 = (const float*)d_in[4];
    const float* b1  = (const float*)d_in[5];
    const float* W2  = (const float*)d_in[6];
    const float* as2 = (const float*)d_in[7];
    const float* ad2 = (const float*)d_in[8];
    const float* b2  = (const float*)d_in[9];
    const float* Wl  = (const float*)d_in[10];
    const float* bl  = (const float*)d_in[11];
    float* out = (float*)d_out;

    // ---- workspace layout (~30 MB) ----
    float* ws = (float*)d_ws;
    size_t o = 0;
    u16* hb  = (u16*)(ws + o); o += (size_t)NN * 64;  // h1 [NN][128] row-major / h2 [2][NN][32] + g2
    u16* g2  = hb + (size_t)NN * 64;                  // g2 [2][NN][32] (upper half of hb)
    u16* g1  = (u16*)(ws + o); o += (size_t)NN * 64;  // g1 [4][NN][32]; bbuf overlay; A2 overlay
    unsigned* bbuf = (unsigned*)g1;                   // 9.63 MB <= 12.8 MB (until bucket_csr)
    unsigned* A2 = (unsigned*)g1;                     // 6.6 MB (after gemm2 consumed g1)
    float* dn2inv = (float*)((char*)g1 + (size_t)EP * 4);  // +200 KB, still in g1
    u16* w1t = (u16*)(ws + o); o += 144 * 256 / 2;    // bf16 W1^T+att [144][256]
    u16* w2t = (u16*)(ws + o); o += 80 * 128 / 2;     // bf16 W2^T+att [80][128]
    u16* wlt = (u16*)(ws + o); o += 16 * 64 / 2;      // bf16 Wl^T padded [16][64]
    float* a_s = ws + o;       o += (size_t)NN * 2;
    float* a_d = ws + o;       o += (size_t)NN * 2;
    int* ints = (int*)(ws + o);
    size_t io = 0;
    int* gcursor  = ints + io; io += NBKT;
    int* row_ptr  = ints + io; io += NN + 1;
    u16* csr_src  = (u16*)(ints + io); io += (EP + 1) / 2;

    // ---- CSR build ----
    hipMemsetAsync(gcursor, 0, NBKT * sizeof(int), stream);
    partition_k<<<NPB, 1024, 0, stream>>>(ei, gcursor, bbuf,
                                          W1, as1, ad1, w1t, W2, as2, ad2, w2t,
                                          Wl, wlt);
    bucket_csr_k<<<NBKT, 1024, 0, stream>>>(bbuf, gcursor, row_ptr, csr_src);

    const int gemmBlocks = (NN + 63) / 64;  // 782
    const int gatherBlocks = (NN + 3) / 4;  // 4 waves (nodes) per 256-thread block

    // ---- layer 1: GATConv(256 -> 64, heads=2, concat) + ELU ----
    gemm_mfma_att_k<256, 128, 2, true, false, false><<<gemmBlocks, 256, 0, stream>>>(
        x, nullptr, w1t, hb, a_s, a_d);
    gat_gather_k<128, 2, false><<<gatherBlocks, 256, 0, stream>>>(
        row_ptr, csr_src, a_s, a_d, hb, b1, g1, nullptr, nullptr, nullptr);

    // ---- layer 2: GATConv(128 -> 64, heads=1) + ELU ----
    gemm_mfma_att_k<128, 64, 1, false, true, true><<<gemmBlocks, 256, 0, stream>>>(
        nullptr, g1, w2t, hb, a_s, a_d);
    edge_alpha_k<<<(NN / 2 + 3) / 4, 256, 0, stream>>>(
        row_ptr, csr_src, a_s, a_d, A2, dn2inv);
    // 2 slices x 4 XCDs; (b>>3) in [0,1563) x SUB=4 -> grid 12504
    gat_slice_k<64, 2, 1, true><<<12504, 256, 0, stream>>>(
        row_ptr, csr_src, A2, nullptr, nullptr, dn2inv, hb, b2, g2);

    // ---- fused head: out = elu-output @ Wl + bl ----
    head_gemm_k<<<gemmBlocks, 256, 0, stream>>>(g2, wlt, bl, out);
}

// Round 13
// 300.070 us; speedup vs baseline: 1.0664x; 1.0100x over previous
//
#include <hip/hip_runtime.h>

#define NN 50000
#define NE 1600000
#define EP (NE + NN)   // edges + self loops
#define IN_DIM 256
#define HIDD 64
#define NCLS 10
#define NBKT 196                       // destination buckets: d >> 8
#define EPB 8192                       // edges per partition block
#define NPB ((EP + EPB - 1) / EPB)     // 202 partition blocks
#define BCAP 12288                     // fixed bucket capacity (exp 8418 +- 92)

typedef unsigned short u16;
typedef short bf16x8 __attribute__((ext_vector_type(8)));
typedef float f32x4 __attribute__((ext_vector_type(4)));

__device__ __forceinline__ float b2f(u16 v) { return __uint_as_float(((unsigned)v) << 16); }
__device__ __forceinline__ u16 f2b(float f) {
    unsigned u = __float_as_uint(f);
    unsigned r = (u + 0x7FFFu + ((u >> 16) & 1u)) >> 16;
    return (u16)r;
}

__device__ __forceinline__ void load_edge(const int* __restrict__ ei, int m, int g,
                                          int& s, int& d) {
    if (g < NE) {
        if (m) { s = ei[2 * (size_t)g]; d = ei[2 * ((size_t)NE + g)]; }
        else   { s = ei[g];             d = ei[NE + g]; }
    } else {
        s = d = g - NE;  // self loop
    }
    s = s < 0 ? 0 : (s >= NN ? NN - 1 : s);
    d = d < 0 ? 0 : (d >= NN ? NN - 1 : d);
}

// ---- weight transpose + augmented score rows (device helper) ----
__device__ __forceinline__ void wcvt_att_job(
    const float* __restrict__ W, const float* __restrict__ as,
    const float* __restrict__ ad, int K, int N, int H, u16* __restrict__ Wt,
    int idx) {
    if (idx >= K * (N + 16)) return;
    int n = idx / K, k = idx - n * K;
    if (n < N) { Wt[idx] = f2b(W[(size_t)k * N + n]); return; }
    int j = n - N;
    if (j >= 2 * H) { Wt[idx] = 0; return; }
    const float* att = (j & 1) ? ad : as;
    int h = j >> 1, C = N / H;
    float sum = 0.f;
    for (int c = 0; c < C; ++c)
        sum += W[(size_t)k * N + h * C + c] * att[h * C + c];
    Wt[idx] = f2b(sum);
}

// ---- partition pass: LDS counting-sort per block -> COALESCED bbuf writes ----
__global__ __launch_bounds__(1024) void partition_k(
    const int* __restrict__ ei, int* __restrict__ gcursor,
    unsigned* __restrict__ bbuf,
    const float* __restrict__ W1, const float* __restrict__ as1,
    const float* __restrict__ ad1, u16* __restrict__ w1t,
    const float* __restrict__ W2, const float* __restrict__ as2,
    const float* __restrict__ ad2, u16* __restrict__ w2t,
    const float* __restrict__ Wl, u16* __restrict__ wlt) {
    __shared__ int hist[NBKT], base[NBKT], lbase[NBKT], lcur[NBKT];
    __shared__ int psc[256];
    __shared__ unsigned sst[EPB];
    __shared__ int smode;
    int t = threadIdx.x, b = blockIdx.x;
    // side jobs: W1 on blocks 0..35, W2 on 36..45, Wl transpose on 46
    if (b < 36) wcvt_att_job(W1, as1, ad1, 256, 128, 2, w1t, b * 1024 + t);
    else if (b < 46) wcvt_att_job(W2, as2, ad2, 128, 64, 1, w2t, (b - 36) * 1024 + t);
    else if (b == 46) {
        int n = t >> 6, k = t & 63;  // wlt[16][64] = Wl^T padded
        wlt[n * 64 + k] = (n < NCLS) ? f2b(Wl[k * NCLS + n]) : (u16)0;
    }
    // local dtype detect (wave 0)
    if (t < 64) {
        int nz = 0;
#pragma unroll
        for (int k = 0; k < 4; ++k)
            if (ei[2 * (t * 4 + k) + 1] != 0) nz = 1;
        unsigned long long bal = __ballot(nz);
        if (t == 0) smode = (bal == 0ULL) ? 1 : 0;  // 1 = int64 layout
    }
    for (int i = t; i < NBKT; i += 1024) hist[i] = 0;
    __syncthreads();
    int m = smode;
    int g0 = b * EPB;
    int gend = min(g0 + EPB, EP);
    // pass A: histogram
    for (int g = g0 + t; g < gend; g += 1024) {
        int s, d;
        load_edge(ei, m, g, s, d);
        atomicAdd(&hist[d >> 8], 1);
    }
    __syncthreads();
    // exclusive scan of hist -> lbase; claim global bucket ranges -> base
    int hv = 0;
    if (t < 256) { hv = (t < NBKT) ? hist[t] : 0; psc[t] = hv; }
    __syncthreads();
    for (int off = 1; off < 256; off <<= 1) {
        int x = (t < 256 && t >= off) ? psc[t - off] : 0;
        __syncthreads();
        if (t < 256) psc[t] += x;
        __syncthreads();
    }
    if (t < NBKT) {
        lbase[t] = psc[t] - hv;
        lcur[t] = 0;
        base[t] = hv ? atomicAdd(&gcursor[t], hv) : 0;
    }
    __syncthreads();
    // pass B: re-read edges, scatter into LDS sorted-by-bucket order
    for (int g = g0 + t; g < gend; g += 1024) {
        int s, d;
        load_edge(ei, m, g, s, d);
        unsigned p = ((unsigned)s << 16) | (unsigned)d;
        int bb = d >> 8;
        int r = lbase[bb] + atomicAdd(&lcur[bb], 1);
        sst[r] = p;
    }
    __syncthreads();
    // pass C: coalesced global write (consecutive l in same bucket)
    int cnt = gend - g0;
    for (int l = t; l < cnt; l += 1024) {
        unsigned p = sst[l];
        int bb = (p & 0xFFFF) >> 8;
        int gp = base[bb] + (l - lbase[bb]);
        if (gp < BCAP)  // harden: adversarial skew can't write OOB
            bbuf[(size_t)bb * BCAP + gp] = ((p >> 16) << 8) | (p & 255u);
    }
}

// ---- per-bucket fine CSR; SINGLE bbuf read (register stash) ----
// Round-13: the sort pass previously re-read 26 MB of bbuf from global;
// now each thread stashes its <=12 entries in registers during the
// histogram pass and scatters from registers (same trick as partition B).
__global__ __launch_bounds__(1024) void bucket_csr_k(const unsigned* __restrict__ bbuf,
                                                     const int* __restrict__ gcursor,
                                                     int* __restrict__ row_ptr,
                                                     u16* __restrict__ csr_src) {
    __shared__ int bsc[256];
    __shared__ int hist[256], scn[256], cur[256];
    __shared__ int se0, scnt, stot;
    __shared__ u16 srt[BCAP];
    int b = blockIdx.x, t = threadIdx.x;
    int v = 0;
    if (t < 256) {
        v = (t < NBKT) ? min(gcursor[t], BCAP) : 0;
        bsc[t] = v;
        hist[t] = 0;
    }
    __syncthreads();
    for (int off = 1; off < 256; off <<= 1) {
        int x = (t < 256 && t >= off) ? bsc[t - off] : 0;
        __syncthreads();
        if (t < 256) bsc[t] += x;
        __syncthreads();
    }
    if (t == b) { se0 = bsc[t] - v; scnt = v; }
    if (t == NBKT - 1) stot = bsc[t];
    __syncthreads();
    int e0 = se0, cnt = scnt;
    const unsigned* bb = bbuf + (size_t)b * BCAP;
    unsigned ed[BCAP / 1024];  // 12 regs
#pragma unroll
    for (int i = 0; i < BCAP / 1024; ++i) {
        int e = t + i * 1024;
        if (e < cnt) {
            unsigned p = bb[e];
            ed[i] = p;
            atomicAdd(&hist[p & 255], 1);
        } else {
            ed[i] = 0xFFFFFFFFu;  // s<=49999 -> p < 0xC35FFF, never collides
        }
    }
    __syncthreads();
    int hv = 0;
    if (t < 256) { hv = hist[t]; scn[t] = hv; }
    __syncthreads();
    for (int off = 1; off < 256; off <<= 1) {
        int x = (t < 256 && t >= off) ? scn[t - off] : 0;
        __syncthreads();
        if (t < 256) scn[t] += x;
        __syncthreads();
    }
    if (t < 256) {
        int ex = scn[t] - hv;  // exclusive within bucket (LOCAL offset)
        int n = b * 256 + t;
        if (n < NN) row_ptr[n] = e0 + ex;
        cur[t] = ex;
    }
    __syncthreads();
    // sort into LDS by node from REGISTERS, then write csr_src coalesced
#pragma unroll
    for (int i = 0; i < BCAP / 1024; ++i) {
        unsigned p = ed[i];
        if (p != 0xFFFFFFFFu) {
            int pos = atomicAdd(&cur[p & 255], 1);
            srt[pos] = (u16)(p >> 8);
        }
    }
    __syncthreads();
    for (int e = t; e < cnt; e += 1024)
        csr_src[e0 + e] = srt[e];
    if (b == 0 && t == 0) row_ptr[NN] = stot;
}

// ---- MFMA GEMM + fused scores; C row-major or slice-major [NF/32][NN][32] ----
template <int K, int NF, int H, bool F32A, bool SLICED_A, bool SLICED_C>
__global__ __launch_bounds__(256) void gemm_mfma_att_k(
    const float* __restrict__ Af, const u16* __restrict__ Ab,
    const u16* __restrict__ Wt, u16* __restrict__ C,
    float* __restrict__ a_s, float* __restrict__ a_d) {
    constexpr int NTF = NF / 16, NT = NTF + 1, KS = K / 32;
    const int wave = threadIdx.x >> 6, lane = threadIdx.x & 63;
    const int quad = lane >> 4, l15 = lane & 15;
    const int m0 = blockIdx.x * 64 + wave * 16;
    int rowA = m0 + l15;
    if (rowA >= NN) rowA = NN - 1;
    const float* afp = F32A ? (Af + (size_t)rowA * K + quad * 8) : nullptr;
    const u16* abp = nullptr;
    if constexpr (!F32A) {
        abp = SLICED_A ? (Ab + (size_t)rowA * 32 + quad * 8)
                       : (Ab + (size_t)rowA * K + quad * 8);
    }
    const u16* bptr = Wt + (size_t)l15 * K + quad * 8;
    f32x4 acc[NT] = {};
#pragma unroll
    for (int ks = 0; ks < KS; ++ks) {
        bf16x8 af;
        if constexpr (F32A) {
            float4 v0 = *(const float4*)(afp + ks * 32);
            float4 v1 = *(const float4*)(afp + ks * 32 + 4);
            af[0] = (short)f2b(v0.x); af[1] = (short)f2b(v0.y);
            af[2] = (short)f2b(v0.z); af[3] = (short)f2b(v0.w);
            af[4] = (short)f2b(v1.x); af[5] = (short)f2b(v1.y);
            af[6] = (short)f2b(v1.z); af[7] = (short)f2b(v1.w);
        } else {
            af = SLICED_A ? *(const bf16x8*)(abp + (size_t)ks * (NN * 32))
                          : *(const bf16x8*)(abp + ks * 32);
        }
        bf16x8 bf[NT];
#pragma unroll
        for (int nt = 0; nt < NT; ++nt)
            bf[nt] = *(const bf16x8*)(bptr + (size_t)nt * 16 * K + ks * 32);
#pragma unroll
        for (int nt = 0; nt < NT; ++nt)
            acc[nt] = __builtin_amdgcn_mfma_f32_16x16x32_bf16(af, bf[nt], acc[nt], 0, 0, 0);
    }
#pragma unroll
    for (int nt = 0; nt < NTF; ++nt) {
#pragma unroll
        for (int reg = 0; reg < 4; ++reg) {
            int row = m0 + quad * 4 + reg;
            int c = nt * 16 + l15;
            if (row < NN) {
                if constexpr (SLICED_C)
                    C[(size_t)(c >> 5) * (NN * 32) + (size_t)row * 32 + (c & 31)] =
                        f2b(acc[nt][reg]);
                else
                    C[(size_t)row * NF + c] = f2b(acc[nt][reg]);
            }
        }
    }
    if (l15 < 2 * H) {
        int h = l15 >> 1;
        float* dst = (l15 & 1) ? a_d : a_s;
#pragma unroll
        for (int reg = 0; reg < 4; ++reg) {
            int row = m0 + quad * 4 + reg;
            if (row < NN) dst[row * H + h] = acc[NTF][reg];
        }
    }
}

// ---- layer-1 fused gather (roofline-verified 64us): one WAVE per node ----
// Full 256B h-row per edge via 64x4B lanes; JB=16 readlane broadcast.
// Output store is SLICE-MAJOR [4][NN][32] for gemm2's SLICED_A path.
template <int CH, int H, bool HEAD>
__global__ __launch_bounds__(256) void gat_gather_k(
    const int* __restrict__ row_ptr, const u16* __restrict__ csr_src,
    const float* __restrict__ a_s, const float* __restrict__ a_d,
    const u16* __restrict__ h, const float* __restrict__ bias,
    u16* __restrict__ outg, const float* __restrict__ Wl,
    const float* __restrict__ bl, float* __restrict__ outh) {
    constexpr int VEC = CH / 64;
    constexpr int JB = 16;
    int n = (blockIdx.x * blockDim.x + threadIdx.x) >> 6;  // global wave id = node
    int lane = threadIdx.x & 63;
    if (n >= NN) return;  // wave-uniform exit
    int r0 = row_ptr[n], r1 = row_ptr[n + 1];
    const bool hi = (VEC == 2) ? (lane >= 32) : false;
    const int shl16 = hi ? 0 : 16;  // select my head's bf16 ex into bits 31..16

    float adn0, adn1 = 0.f;
    if (H == 2) {
        float2 adv = *(const float2*)(a_d + n * 2);
        adn0 = adv.x; adn1 = adv.y;
    } else {
        adn0 = a_d[n];
    }

    float dh0 = 0.f, dh1 = 0.f;
    float acc[VEC];
#pragma unroll
    for (int v = 0; v < VEC; ++v) acc[v] = 0.f;

    for (int base = r0; base < r1; base += 64) {
        int cnt = min(64, r1 - base);
        int idx = base + lane;
        bool act = idx < r1;
        int sl = act ? (int)csr_src[idx] : 0;
        unsigned pex;   // H==2: bf16(ex0)|bf16(ex1)<<16 ; H==1: s|bf16(ex)<<16
        if (H == 2) {
            float2 av = *(const float2*)(a_s + sl * 2);
            float e0 = av.x + adn0;
            e0 = e0 > 0.f ? e0 : 0.2f * e0;
            e0 = fminf(e0, 60.f);
            float ex0 = act ? __expf(e0) : 0.f;
            dh0 += ex0;
            float e1 = av.y + adn1;
            e1 = e1 > 0.f ? e1 : 0.2f * e1;
            e1 = fminf(e1, 60.f);
            float ex1 = act ? __expf(e1) : 0.f;
            dh1 += ex1;
            pex = (unsigned)f2b(ex0) | ((unsigned)f2b(ex1) << 16);
        } else {
            float e0 = a_s[sl] + adn0;
            e0 = e0 > 0.f ? e0 : 0.2f * e0;
            e0 = fminf(e0, 60.f);
            float ex0 = act ? __expf(e0) : 0.f;
            dh0 += ex0;
            pex = (unsigned)sl | ((unsigned)f2b(ex0) << 16);
        }
        for (int j0 = 0; j0 < cnt; j0 += JB) {
            if (VEC == 2) {
                int ssu[JB];
                unsigned peu[JB];
#pragma unroll
                for (int i = 0; i < JB; ++i) {
                    ssu[i] = __builtin_amdgcn_readlane(sl, j0 + i);
                    peu[i] = (unsigned)__builtin_amdgcn_readlane((int)pex, j0 + i);
                }
                unsigned hv[JB];
#pragma unroll
                for (int i = 0; i < JB; ++i)
                    hv[i] = ((const unsigned*)(h + (size_t)ssu[i] * CH))[lane];
#pragma unroll
                for (int i = 0; i < JB; ++i) {
                    float exv = __uint_as_float((peu[i] << shl16) & 0xFFFF0000u);
                    acc[0] += exv * __uint_as_float(hv[i] << 16);
                    acc[1] += exv * __uint_as_float(hv[i] & 0xFFFF0000u);
                }
            } else {
                unsigned peu[JB];
#pragma unroll
                for (int i = 0; i < JB; ++i)
                    peu[i] = (unsigned)__builtin_amdgcn_readlane((int)pex, j0 + i);
                u16 hv[JB];
#pragma unroll
                for (int i = 0; i < JB; ++i)
                    hv[i] = (h + (size_t)(peu[i] & 0xFFFFu) * CH)[lane];
#pragma unroll
                for (int i = 0; i < JB; ++i)
                    acc[0] += __uint_as_float(peu[i] & 0xFFFF0000u) * b2f(hv[i]);
            }
        }
    }

#pragma unroll
    for (int off = 32; off; off >>= 1) dh0 += __shfl_xor(dh0, off);
    float dn = dh0;
    if (H == 2) {
#pragma unroll
        for (int off = 32; off; off >>= 1) dh1 += __shfl_xor(dh1, off);
        dn = hi ? dh1 : dh0;
    }

    if (VEC == 2) {
        int c = lane * 2;
        float2 bv = *(const float2*)(bias + c);
        float v0 = acc[0] / dn + bv.x;
        float v1 = acc[1] / dn + bv.y;
        v0 = v0 > 0.f ? v0 : expm1f(v0);
        v1 = v1 > 0.f ? v1 : expm1f(v1);
        ushort2 ov;
        ov.x = f2b(v0); ov.y = f2b(v1);
        // slice-major store: slice = c>>5, offset within = c&31
        *(ushort2*)(outg + (size_t)(c >> 5) * (NN * 32) + (size_t)n * 32 + (c & 31)) = ov;
    } else {
        float v0 = acc[0] / dn + bias[lane];
        v0 = v0 > 0.f ? v0 : expm1f(v0);
        if (HEAD) {
#pragma unroll
            for (int cls = 0; cls < NCLS; ++cls) {
                float p = v0 * Wl[lane * NCLS + cls];
#pragma unroll
                for (int off = 32; off; off >>= 1) p += __shfl_xor(p, off);
                if (lane == cls) outh[(size_t)n * NCLS + cls] = p + bl[cls];
            }
        } else {
            outg[(size_t)n * CH + lane] = f2b(v0);
        }
    }
}

// ---- layer-2 slice gather with XCD-L2 affinity ----
// Round-13: USE_EX=false — recompute ex in-kernel (a_s2 is 200 KB, L2-hot
// on every XCD) and drop the edge_alpha dispatch entirely. Numerics are
// bit-identical to the alpha-precompute path (same accumulation order,
// same bf16 rounding of the numerator ex, full-precision denominator).
template <int CH, int NSL, int H, bool USE_EX>
__global__ __launch_bounds__(256) void gat_slice_k(
    const int* __restrict__ row_ptr, const u16* __restrict__ csr_src,
    const unsigned* __restrict__ A2, const float* __restrict__ a_s,
    const float* __restrict__ a_d, const float* __restrict__ dninv,
    const u16* __restrict__ h, const float* __restrict__ bias,
    u16* __restrict__ outg) {
    constexpr int SC = CH / NSL;   // 32 channels (64 B) per slice
    constexpr int SUB = 8 / NSL;   // XCDs per slice
    int xcd = blockIdx.x & 7;
    int slice = xcd / SUB;
    int sub = xcd % SUB;
    int pg = (blockIdx.x >> 3) * SUB + sub;
    int wave = threadIdx.x >> 6;
    int pair = pg * 4 + wave;
    if (pair >= NN / 2) return;  // wave-uniform
    int lane = threadIdx.x & 63;
    int half = lane >> 5, hl = lane & 31, q = hl & 7, gh = hl >> 3;
    int node = pair * 2 + half;
    int r0 = row_ptr[node], r1 = row_ptr[node + 1];
    int cnt = r1 - r0;
    int co = max(cnt, __shfl_xor(cnt, 32));
    int nbat = (co + 31) >> 5;
    const unsigned char* hb8 =
        (const unsigned char*)h + (size_t)slice * (NN * 64);
    const int head = (H == 2) ? (slice >> 1) : 0;
    float adn = 0.f, rdn = 0.f;
    if constexpr (USE_EX) rdn = dninv[node];
    else adn = a_d[node * H + head];
    float dh = 0.f;
    float acc[4] = {0.f, 0.f, 0.f, 0.f};
    const int abase = ((half << 5) | gh) << 2;
    for (int b = 0; b < nbat; ++b) {
        int idx = r0 + b * 32 + hl;
        bool act = idx < r1;
        unsigned pex;
        if constexpr (USE_EX) {
            pex = act ? __builtin_nontemporal_load(A2 + idx) : 0u;
        } else {
            int sl = act ? (int)__builtin_nontemporal_load(csr_src + idx) : 0;
            float e = a_s[sl * H + head] + adn;
            e = e > 0.f ? e : 0.2f * e;
            e = fminf(e, 60.f);
            float ex = act ? __expf(e) : 0.f;
            dh += ex;
            pex = (unsigned)sl | ((unsigned)f2b(ex) << 16);
        }
#pragma unroll
        for (int jr = 0; jr < 2; ++jr) {
            int pr[4];
#pragma unroll
            for (int i = 0; i < 4; ++i)
                pr[i] = __builtin_amdgcn_ds_bpermute(
                    abase + ((jr * 16 + i * 4) << 2), (int)pex);
            unsigned hv0[4], hv1[4];
#pragma unroll
            for (int i = 0; i < 4; ++i) {
                const unsigned* p = (const unsigned*)(
                    hb8 + (((unsigned)((unsigned)pr[i] & 0xFFFFu) << 6) + q * 8));
                hv0[i] = p[0];
                hv1[i] = p[1];
            }
#pragma unroll
            for (int i = 0; i < 4; ++i) {
                float exf = __uint_as_float((unsigned)pr[i] & 0xFFFF0000u);
                unsigned w0 = hv0[i], w1 = hv1[i];
                acc[0] += exf * __uint_as_float(w0 << 16);
                acc[1] += exf * __uint_as_float(w0 & 0xFFFF0000u);
                acc[2] += exf * __uint_as_float(w1 << 16);
                acc[3] += exf * __uint_as_float(w1 & 0xFFFF0000u);
            }
        }
    }
    if constexpr (!USE_EX) {
#pragma unroll
        for (int off = 1; off < 32; off <<= 1) dh += __shfl_xor(dh, off);
        rdn = 1.0f / dh;
    }
#pragma unroll
    for (int v = 0; v < 4; ++v) {
        acc[v] += __shfl_xor(acc[v], 8);
        acc[v] += __shfl_xor(acc[v], 16);
    }
    if (gh == 0) {
        float vv[4];
#pragma unroll
        for (int k = 0; k < 4; ++k) {
            float t = acc[k] * rdn + bias[slice * SC + q * 4 + k];
            vv[k] = t > 0.f ? t : expm1f(t);
        }
        unsigned long long ov =
            (unsigned long long)((unsigned)f2b(vv[0]) | ((unsigned)f2b(vv[1]) << 16)) |
            ((unsigned long long)((unsigned)f2b(vv[2]) | ((unsigned)f2b(vv[3]) << 16)) << 32);
        __builtin_nontemporal_store(
            ov, (unsigned long long*)(outg + (size_t)slice * (NN * 32) +
                                      (size_t)node * 32 + q * 4));
    }
}

// ---- head: out[NN][10] = g2[NN][64] (sliced bf16) @ Wl + bl via MFMA ----
__global__ __launch_bounds__(256) void head_gemm_k(
    const u16* __restrict__ A, const u16* __restrict__ Wt,
    const float* __restrict__ bl, float* __restrict__ out) {
    const int wave = threadIdx.x >> 6, lane = threadIdx.x & 63;
    const int quad = lane >> 4, l15 = lane & 15;
    const int m0 = blockIdx.x * 64 + wave * 16;
    int rowA = m0 + l15;
    if (rowA >= NN) rowA = NN - 1;
    const u16* ab = A + (size_t)rowA * 32 + quad * 8;
    const u16* bp = Wt + (size_t)l15 * 64 + quad * 8;
    f32x4 acc = {};
#pragma unroll
    for (int ks = 0; ks < 2; ++ks) {
        bf16x8 af = *(const bf16x8*)(ab + (size_t)ks * (NN * 32));
        bf16x8 bf = *(const bf16x8*)(bp + ks * 32);
        acc = __builtin_amdgcn_mfma_f32_16x16x32_bf16(af, bf, acc, 0, 0, 0);
    }
    if (l15 < NCLS) {
        float blv = bl[l15];
#pragma unroll
        for (int reg = 0; reg < 4; ++reg) {
            int row = m0 + quad * 4 + reg;
            if (row < NN) out[(size_t)row * NCLS + l15] = acc[reg] + blv;
        }
    }
}

extern "C" void kernel_launch(void* const* d_in, const int* in_sizes, int n_in,
                              void* d_out, int out_size, void* d_ws, size_t ws_size,
                              hipStream_t stream) {
    const float* x   = (const float*)d_in[0];
    const int*   ei  = (const int*)d_in[1];
    const float* W1  = (const float*)d_in[2];
    const float* as1 = (const float*)d_in[3];
    const float* ad1 = (const float*)d_in[4];
    const float* b1  = (const float*)d_in[5];
    const float* W2  = (const float*)d_in[6];
    const float* as2 = (const float*)d_in[7];
    const float* ad2 = (const float*)d_in[8];
    const float* b2  = (const float*)d_in[9];
    const float* Wl  = (const float*)d_in[10];
    const float* bl  = (const float*)d_in[11];
    float* out = (float*)d_out;

    // ---- workspace layout (~30 MB) ----
    float* ws = (float*)d_ws;
    size_t o = 0;
    u16* hb  = (u16*)(ws + o); o += (size_t)NN * 64;  // h1 [NN][128] row-major / h2 [2][NN][32] + g2
    u16* g2  = hb + (size_t)NN * 64;                  // g2 [2][NN][32] (upper half of hb)
    u16* g1  = (u16*)(ws + o); o += (size_t)NN * 64;  // g1 [4][NN][32]; bbuf overlay
    unsigned* bbuf = (unsigned*)g1;                   // 9.63 MB <= 12.8 MB (until bucket_csr)
    u16* w1t = (u16*)(ws + o); o += 144 * 256 / 2;    // bf16 W1^T+att [144][256]
    u16* w2t = (u16*)(ws + o); o += 80 * 128 / 2;     // bf16 W2^T+att [80][128]
    u16* wlt = (u16*)(ws + o); o += 16 * 64 / 2;      // bf16 Wl^T padded [16][64]
    float* a_s = ws + o;       o += (size_t)NN * 2;
    float* a_d = ws + o;       o += (size_t)NN * 2;
    int* ints = (int*)(ws + o);
    size_t io = 0;
    int* gcursor  = ints + io; io += NBKT;
    int* row_ptr  = ints + io; io += NN + 1;
    u16* csr_src  = (u16*)(ints + io); io += (EP + 1) / 2;

    // ---- CSR build ----
    hipMemsetAsync(gcursor, 0, NBKT * sizeof(int), stream);
    partition_k<<<NPB, 1024, 0, stream>>>(ei, gcursor, bbuf,
                                          W1, as1, ad1, w1t, W2, as2, ad2, w2t,
                                          Wl, wlt);
    bucket_csr_k<<<NBKT, 1024, 0, stream>>>(bbuf, gcursor, row_ptr, csr_src);

    const int gemmBlocks = (NN + 63) / 64;  // 782
    const int gatherBlocks = (NN + 3) / 4;  // 4 waves (nodes) per 256-thread block

    // ---- layer 1: GATConv(256 -> 64, heads=2, concat) + ELU ----
    gemm_mfma_att_k<256, 128, 2, true, false, false><<<gemmBlocks, 256, 0, stream>>>(
        x, nullptr, w1t, hb, a_s, a_d);
    gat_gather_k<128, 2, false><<<gatherBlocks, 256, 0, stream>>>(
        row_ptr, csr_src, a_s, a_d, hb, b1, g1, nullptr, nullptr, nullptr);

    // ---- layer 2: GATConv(128 -> 64, heads=1) + ELU ----
    gemm_mfma_att_k<128, 64, 1, false, true, true><<<gemmBlocks, 256, 0, stream>>>(
        nullptr, g1, w2t, hb, a_s, a_d);
    // slice gather recomputes alpha in-kernel (edge_alpha dispatch removed)
    gat_slice_k<64, 2, 1, false><<<12504, 256, 0, stream>>>(
        row_ptr, csr_src, nullptr, a_s, a_d, nullptr, hb, b2, g2);

    // ---- fused head: out = elu-output @ Wl + bl ----
    head_gemm_k<<<gemmBlocks, 256, 0, stream>>>(g2, wlt, bl, out);
}